// Round 7
// baseline (966.452 us; speedup 1.0000x reference)
//
#include <hip/hip_runtime.h>
#include <hip/hip_cooperative_groups.h>
#include <math.h>

namespace cg = cooperative_groups;

#define PI_F 3.14159265358979323846f

__device__ __forceinline__ float gelu_exact(float v) {
    return 0.5f * v * (1.0f + erff(v * 0.70710678118654752f));
}
__device__ __forceinline__ int rfl(int x) { return __builtin_amdgcn_readfirstlane(x); }

__device__ __forceinline__ unsigned short f2bf(float f) {   // RNE fp32->bf16
    unsigned int u = __float_as_uint(f);
    u += 0x7fffu + ((u >> 16) & 1u);
    return (unsigned short)(u >> 16);
}
__device__ __forceinline__ float bf2f(unsigned short h) {
    return __uint_as_float(((unsigned int)h) << 16);
}

// XCD-locality swizzle for 8192-block grids (blk%8 -> XCD round-robin).
__device__ __forceinline__ void swz8k(int blk, int& b, int& nx, int& ny) {
    int x = blk & 7;
    int j = blk >> 3;
    int pair = x * 16 + (j >> 6);
    ny = j & 63;
    b = pair >> 6;
    nx = pair & 63;
}

// Radix-8 stage A: 8-pt real DFT; write layout [j][t] pitch 257 -> banks (j+t)%32 (2-way, free)
__device__ __forceinline__ void rdft8(const float h[8], float* __restrict__ hr,
                                      float* __restrict__ hi, int t) {
    const float s2 = 0.70710678118654752f;
    float e0 = h[0] + h[4], e1 = h[1] + h[5], e2 = h[2] + h[6], e3 = h[3] + h[7];
    float o0 = h[0] - h[4], o1 = h[1] - h[5], o2 = h[2] - h[6], o3 = h[3] - h[7];
    float ee = e0 + e2, eo = e1 + e3;
    float H0r = ee + eo, H4r = ee - eo;
    float H2r = e0 - e2, H2i = -(e1 - e3);
    float t13p = s2 * (o1 + o3), t13m = s2 * (o1 - o3);
    float H1r = o0 + t13m, H1i = -o2 - t13p;
    float H3r = o0 - t13m, H3i =  o2 - t13p;
    hr[0 * 257 + t] = H0r;  hi[0 * 257 + t] = 0.0f;
    hr[1 * 257 + t] = H1r;  hi[1 * 257 + t] = H1i;
    hr[2 * 257 + t] = H2r;  hi[2 * 257 + t] = H2i;
    hr[3 * 257 + t] = H3r;  hi[3 * 257 + t] = H3i;
    hr[4 * 257 + t] = H4r;  hi[4 * 257 + t] = 0.0f;
    hr[5 * 257 + t] = H3r;  hi[5 * 257 + t] = -H3i;
    hr[6 * 257 + t] = H2r;  hi[6 * 257 + t] = -H2i;
    hr[7 * 257 + t] = H1r;  hi[7 * 257 + t] = -H1i;
}

// Radix-8 stage B with LDS twiddle tables (kz*q < 64, broadcast reads)
__device__ __forceinline__ float2 zdft_combine(const float* __restrict__ hr,
                                               const float* __restrict__ hi,
                                               const float* __restrict__ cosT,
                                               const float* __restrict__ sinT,
                                               int o, int kz) {
    float re = 0.0f, im = 0.0f;
    int base = kz * 257 + o * 8;
    #pragma unroll
    for (int q = 0; q < 8; q++) {
        float Hr = hr[base + q], Hi = hi[base + q];
        int m = (kz * q) & 63;
        float c = cosT[m], s = sinT[m];
        re += Hr * c + Hi * s;          // H * e^{-i kz q pi/32}
        im += Hi * c - Hr * s;
    }
    return make_float2(re, im);
}

// ---------------- emb ----------------
__global__ void k_emb(const float* __restrict__ time_i, const float* __restrict__ conditions,
                      const float* __restrict__ t_embed_w, const float* __restrict__ t_embed_b,
                      const float* __restrict__ c_embed_w, const float* __restrict__ c_embed_b,
                      const float* __restrict__ lift_b, float* __restrict__ embk) {
    __shared__ float red[8][32];
    int t = threadIdx.x;
    int b = blockIdx.x;
    int c = t & 31, lg = t >> 5;
    float acc = 0.0f;
    if (lg == 0) {
        acc = t_embed_b[c] + c_embed_b[c] + lift_b[c];
        float tv = time_i[b];
        float ang = PI_F * tv;
        const float* tw = t_embed_w + c * 11;
        for (int i = 0; i < 5; i++) {
            float s, co; sincosf(ang, &s, &co);
            acc += co * tw[i] + s * tw[5 + i];
            ang *= 2.0f;
        }
        acc += tv * tw[10];
    }
    const float* cw = c_embed_w + c * 352;
    for (int j = 0; j < 4; j++) {
        int l = lg * 4 + j;
        float v = conditions[b * 32 + l];
        float ang = PI_F * v;
        for (int i = 0; i < 5; i++) {
            float s, co; sincosf(ang, &s, &co);
            acc += co * cw[l * 10 + i] + s * cw[l * 10 + 5 + i];
            ang *= 2.0f;
        }
        acc += v * cw[320 + l];
    }
    red[lg][c] = acc;
    __syncthreads();
    if (t < 32) {
        float s = 0.0f;
        for (int g = 0; g < 8; g++) s += red[g][t];
        embk[b * 32 + t] = s;
    }
}

// -------- k_wt: transposed byp + lift weights --------
__global__ void k_wt(const float* __restrict__ byp_w, const float* __restrict__ lift_w,
                     float* __restrict__ wtb, float* __restrict__ wlT) {
    int idx = blockIdx.x * 256 + threadIdx.x;
    if (idx < 4096) {
        int l = idx >> 10, rem = idx & 1023;
        int o = rem >> 5, i = rem & 31;
        wtb[(l << 10) + (i << 5) + o] = byp_w[idx];
    } else if (idx < 4096 + 1184) {
        int j = idx - 4096;
        int q = j >> 5, o = j & 31;
        wlT[j] = lift_w[o * 37 + q];
    }
}

// ------- k_lift: lift conv + emb, radix-8 forward z-DFT. x0 in bf16. -------
__global__ __launch_bounds__(256) void k_lift(const float* __restrict__ state_in,
        const float* __restrict__ node_pos, const float* __restrict__ wlT,
        const float* __restrict__ embk, unsigned short* __restrict__ x0,
        float2* __restrict__ a1) {
    __shared__ __align__(16) float S[8784];
    float* fs   = S;             // 2368 [q][nz]
    float* ys   = S + 2368;      // 2176 [o][nz] pitch 68
    float* hr   = S + 4544;      // 2056 [j][t] pitch 257
    float* hi   = S + 6600;      // 2056
    float* cosT = S + 8656;      // 64
    float* sinT = S + 8720;      // 64
    int t = threadIdx.x;
    int b, nx, ny; swz8k(blockIdx.x, b, nx, ny);
    int nxy = nx * 64 + ny;

    if (t < 64) { float s, c; sincosf((float)t * (PI_F / 32.0f), &s, &c); cosT[t] = c; sinT[t] = s; }
    if (t >= 64 && t < 128) {
        int tt = t - 64;
        int n = (nxy << 6) + tt;
        const float4 s4 = *(const float4*)(state_in + ((size_t)b * 262144 + n) * 4);
        fs[0 * 64 + tt] = s4.x; fs[1 * 64 + tt] = s4.y;
        fs[2 * 64 + tt] = s4.z; fs[3 * 64 + tt] = s4.w;
        const float* pp = node_pos + ((size_t)b * 262144 + n) * 3;
        for (int l = 0; l < 3; l++) {
            float p = pp[l];
            float ang = PI_F * p;
            for (int i = 0; i < 5; i++) {
                float s, co; sincosf(ang, &s, &co);
                fs[(4 + l * 10 + i) * 64 + tt] = co;
                fs[(4 + l * 10 + 5 + i) * 64 + tt] = s;
                ang *= 2.0f;
            }
            fs[(34 + l) * 64 + tt] = p;
        }
    }
    __syncthreads();

    int nz = t & 63;
    int wq = rfl(t >> 6);
    float acc[8];
    #pragma unroll
    for (int k = 0; k < 8; k++) acc[k] = embk[b * 32 + wq * 8 + k];
    #pragma unroll
    for (int q = 0; q < 37; q++) {
        float fq = fs[q * 64 + nz];
        const float* w = wlT + q * 32 + wq * 8;
        #pragma unroll
        for (int k = 0; k < 8; k++) acc[k] += w[k] * fq;
    }
    int n = (nxy << 6) + nz;
    #pragma unroll
    for (int k = 0; k < 8; k++) {
        int o = wq * 8 + k;
        x0[(((size_t)(b * 32 + o)) << 18) + n] = f2bf(acc[k]);
        ys[o * 68 + nz] = acc[k];
    }
    __syncthreads();
    {   // stage A
        int o = t >> 3, q = t & 7;
        float h[8];
        #pragma unroll
        for (int p = 0; p < 8; p++) h[p] = ys[o * 68 + 8 * p + q];
        rdft8(h, hr, hi, t);
    }
    __syncthreads();
    {   // stage B
        float2 r = zdft_combine(hr, hi, cosT, sinT, t >> 3, t & 7);
        a1[((size_t)(b * 4096 + nxy)) * 256 + t] = r;
    }
}

// =================== spectral mid-section: 4 phases ===================

// phase1: forward y-DFT partials over ny-halves. a1 -> a2p[half][pair][jj][ky]
__device__ __forceinline__ void phase1(int blk, int t, const float2* __restrict__ a1,
                                       float2* __restrict__ a2p) {
    int x = blk & 7, r = blk >> 3;
    int pair = x * 16 + (r & 15);
    int half = r >> 4;
    const float2* src = a1 + ((size_t)(pair * 64 + half * 32)) * 256 + t;
    float accr[8], acci[8];
    #pragma unroll
    for (int k = 0; k < 8; k++) { accr[k] = 0.0f; acci[k] = 0.0f; }
    const float bc = 0.99518472667f;          // cos(pi/32)
    const float bs = -0.09801714033f;         // -sin(pi/32)
    float wc = half ? -1.0f : 1.0f;           // e^{-i*32*pi/32} = -1
    float ws = 0.0f;
    #pragma unroll 4
    for (int j = 0; j < 32; j++) {
        float2 v = src[(size_t)j * 256];
        accr[0] += v.x; acci[0] += v.y;
        float tc = wc, ts = ws;
        #pragma unroll
        for (int ky = 1; ky < 8; ky++) {
            accr[ky] += v.x * tc - v.y * ts;
            acci[ky] += v.x * ts + v.y * tc;
            float nt = tc * wc - ts * ws; ts = ts * wc + tc * ws; tc = nt;
        }
        float nw = wc * bc - ws * bs; ws = ws * bc + wc * bs; wc = nw;
    }
    float4* dst = (float4*)(a2p + (size_t)half * 262144 + ((size_t)(pair * 256 + t)) * 8);
    #pragma unroll
    for (int j = 0; j < 4; j++)
        dst[j] = make_float4(accr[2 * j], acci[2 * j], accr[2 * j + 1], acci[2 * j + 1]);
}

// phase2: forward x-DFT (sums partials). -> xft[((b*32+c)*8+kz)*64 + ky*8+kx]
__device__ __forceinline__ void phase2(int blk, int t, const float2* __restrict__ a2p,
                                       float2* __restrict__ xft, float2* __restrict__ SH) {
    for (int lu = 0; lu < 2; lu++) {
        int un = blk * 2 + lu;
        int b = un >> 8, ckz = un & 255;
        size_t base = (size_t)b * 131072 + (size_t)ckz * 8;
        for (int e = t; e < 512; e += 256) {
            size_t a = base + (size_t)(e >> 3) * 2048 + (e & 7);
            float2 v0 = a2p[a];
            float2 v1 = a2p[a + 262144];
            SH[lu * 520 + e] = make_float2(v0.x + v1.x, v0.y + v1.y);
        }
    }
    __syncthreads();
    if (t < 128) {
        int lu = t >> 6, out = t & 63;
        int un = blk * 2 + lu;
        int kx = out & 7;
        float sn, cc; sincosf((float)kx * (PI_F / 32.0f), &sn, &cc);
        float bsn = -sn;
        float tc = 1.0f, ts = 0.0f, rr = 0.0f, ri = 0.0f;
        const float2* row = SH + lu * 520 + (out >> 3);
        for (int nx = 0; nx < 64; nx++) {
            float2 v = row[nx * 8];
            rr += v.x * tc - v.y * ts;
            ri += v.x * ts + v.y * tc;
            float nt = tc * cc - ts * bsn; ts = ts * cc + tc * bsn; tc = nt;
        }
        xft[(size_t)un * 64 + out] = make_float2(rr, ri);
    }
}

// phase3: mode mix over i-halves. -> yftp[ih][((b*32+o)*8+kz)*64 + ky*8+kx]
__device__ __forceinline__ void phase3(int blk, int t, const float2* __restrict__ xft,
                                       const float* __restrict__ wr, const float* __restrict__ wi,
                                       float2* __restrict__ yftp, float2* __restrict__ SH) {
    int unit = blk >> 1, ih = blk & 1;
    int b = unit >> 6, kx = (unit >> 3) & 7, ky = unit & 7;
    if (t < 128) {
        int il = t >> 3, kz = t & 7;
        int i = ih * 16 + il;
        SH[t] = xft[((size_t)((b * 32 + i) * 8 + kz)) * 64 + ky * 8 + kx];
    }
    __syncthreads();
    int o = t >> 3, kz = t & 7;
    float yr = 0.0f, yi = 0.0f;
    for (int il = 0; il < 16; il++) {
        int i = ih * 16 + il;
        float2 xv = SH[il * 8 + kz];
        int wofs = ((i * 32 + o) << 9) + kx * 64 + ky * 8 + kz;
        float wrv = wr[wofs], wiv = wi[wofs];
        yr += xv.x * wrv - xv.y * wiv;
        yi += xv.x * wiv + xv.y * wrv;
    }
    yftp[(size_t)ih * 32768 + ((size_t)((b * 32 + o) * 8 + kz)) * 64 + ky * 8 + kx]
        = make_float2(yr, yi);
}

// phase4: inverse x (sums yftp halves). -> b1[b][nx][o*8+kz][ky]
__device__ __forceinline__ void phase4(int blk, int t, const float2* __restrict__ yftp,
                                       float2* __restrict__ b1, float2* __restrict__ SH) {
    for (int u = 0; u < 2; u++) {
        if (u) __syncthreads();
        int unit = blk * 2 + u;
        int b = unit >> 8, nx = (unit >> 2) & 63, og = unit & 3;
        size_t sbase = ((size_t)(b * 32 + og * 8)) * 512;
        for (int e = t; e < 4096; e += 256) {
            float2 v0 = yftp[sbase + e];
            float2 v1 = yftp[32768 + sbase + e];
            SH[(e >> 3) * 9 + (e & 7)] = make_float2(v0.x + v1.x, v0.y + v1.y);
        }
        __syncthreads();
        float cs, ss; sincosf((float)nx * (PI_F / 32.0f), &ss, &cs);
        float2* dst = b1 + ((size_t)(b * 64 + nx)) * 2048 + og * 512;
        for (int h = 0; h < 2; h++) {
            int idx = h * 256 + t;
            const float2* row = SH + idx * 9;
            float c = 1.0f, s = 0.0f, rr = 0.0f, ri = 0.0f;
            #pragma unroll
            for (int kx = 0; kx < 8; kx++) {
                float2 y = row[kx];
                rr += y.x * c - y.y * s;      // e^{+i kx nx θ}
                ri += y.x * s + y.y * c;
                float nc = c * cs - s * ss; s = s * cs + c * ss; c = nc;
            }
            dst[idx] = make_float2(rr, ri);
        }
    }
}

// cooperative all-in-one
__global__ __launch_bounds__(256) void k_spec(const float2* __restrict__ a1,
        float2* __restrict__ a2p, float2* __restrict__ xft, float2* __restrict__ yftp,
        float2* __restrict__ b1, const float* __restrict__ wr, const float* __restrict__ wi) {
    __shared__ __align__(16) float2 SH[4608];
    cg::grid_group gg = cg::this_grid();
    phase1(blockIdx.x, threadIdx.x, a1, a2p);
    gg.sync();
    phase2(blockIdx.x, threadIdx.x, a2p, xft, SH);
    gg.sync();
    phase3(blockIdx.x, threadIdx.x, xft, wr, wi, yftp, SH);
    gg.sync();
    phase4(blockIdx.x, threadIdx.x, yftp, b1, SH);
}

// fallback standalone kernels (used only if cooperative launch is rejected)
__global__ __launch_bounds__(256) void k_p1(const float2* __restrict__ a1,
                                            float2* __restrict__ a2p) {
    phase1(blockIdx.x, threadIdx.x, a1, a2p);
}
__global__ __launch_bounds__(256) void k_p2(const float2* __restrict__ a2p,
                                            float2* __restrict__ xft) {
    __shared__ __align__(16) float2 SH[1040];
    phase2(blockIdx.x, threadIdx.x, a2p, xft, SH);
}
__global__ __launch_bounds__(256) void k_p3(const float2* __restrict__ xft,
        const float* __restrict__ wr, const float* __restrict__ wi,
        float2* __restrict__ yftp) {
    __shared__ __align__(16) float2 SH[128];
    phase3(blockIdx.x, threadIdx.x, xft, wr, wi, yftp, SH);
}
__global__ __launch_bounds__(256) void k_p4(const float2* __restrict__ yftp,
                                            float2* __restrict__ b1) {
    __shared__ __align__(16) float2 SH[4608];
    phase4(blockIdx.x, threadIdx.x, yftp, b1, SH);
}

// ------- k_fin: inverse-y + bypass (bf16 x) + inverse-z + gelu + radix-8 fwd z -------
__global__ __launch_bounds__(256) void k_fin(
        const unsigned short* __restrict__ xin, const float2* __restrict__ b1,
        const float* __restrict__ wt, const float* __restrict__ bb,
        unsigned short* __restrict__ xout, float2* __restrict__ a1, int do_z) {
    __shared__ __align__(16) float S[8080];
    float* b1sr = S;                              // 2112 (dead after inv-y)
    float* b1si = S + 2112;                       // 2112
    float* hr   = S;                              // 2056 alias
    float* hi   = S + 2112;                       // 2056 alias
    unsigned short* xsu = (unsigned short*)(S + 4224);   // 2048 u16
    float2* ms  = (float2*)(S + 5248);            // 256 f2
    float* ys   = S + 5760;                       // 2176 pitch 68
    float2* twy = (float2*)(S + 7936);            // 8 f2
    float* cosT = S + 7952;                       // 64
    float* sinT = S + 8016;                       // 64
    int t = threadIdx.x;
    int b, nx, ny; swz8k(blockIdx.x, b, nx, ny);
    int nxy = nx * 64 + ny;

    if (t < 64) { float s, c; sincosf((float)t * (PI_F / 32.0f), &s, &c); cosT[t] = c; sinT[t] = s; }
    if (t >= 64 && t < 72) {
        int ky = t - 64;
        float s, c; sincosf((float)((ky * ny) & 63) * (PI_F / 32.0f), &s, &c);
        twy[ky] = make_float2(c, s);
    }
    {   // stage x (bf16): one uint4 (8 elems) per thread
        int ch = t >> 3, q = t & 7;
        uint4 v = *(const uint4*)(xin + (((size_t)b) << 23) + (nxy << 6)
                                  + ((size_t)ch << 18) + q * 8);
        *(uint4*)(xsu + ch * 64 + q * 8) = v;
    }
    const float2* bsrc = b1 + ((size_t)(b * 64 + nx)) * 2048;   // contiguous 16 KB
    for (int u = 0; u < 8; u++) {
        int g = u * 256 + t;
        float2 v = bsrc[g];
        int ky = g & 7, okz = g >> 3;
        b1sr[ky * 264 + okz] = v.x;
        b1si[ky * 264 + okz] = v.y;
    }
    __syncthreads();
    {   // inverse-y with block-uniform twiddles
        float mr = 0.0f, mi = 0.0f;
        #pragma unroll
        for (int ky = 0; ky < 8; ky++) {
            float vr = b1sr[ky * 264 + t], vi = b1si[ky * 264 + t];
            float2 w = twy[ky];
            mr += vr * w.x - vi * w.y;        // e^{+i ky ny θ}
            mi += vr * w.y + vi * w.x;
        }
        ms[t] = make_float2(mr, mi);
    }
    __syncthreads();

    int nz = t & 63;
    int wq = rfl(t >> 6);
    float c7[8], s7[8];
    c7[0] = 1.f; s7[0] = 0.f;
    {
        float cs = cosT[nz], ss = sinT[nz];
        #pragma unroll
        for (int kz = 1; kz < 8; kz++) {
            c7[kz] = c7[kz - 1] * cs - s7[kz - 1] * ss;
            s7[kz] = s7[kz - 1] * cs + c7[kz - 1] * ss;
        }
    }
    float acc[8];
    #pragma unroll
    for (int k = 0; k < 8; k++) acc[k] = bb[wq * 8 + k];        // s_load
    #pragma unroll 8
    for (int i = 0; i < 32; i++) {
        float xv = bf2f(xsu[i * 64 + nz]);                      // broadcast-pair ds_read
        const float* wrow = wt + i * 32 + wq * 8;               // s_load_dwordx8
        #pragma unroll
        for (int k = 0; k < 8; k++) acc[k] += wrow[k] * xv;
    }
    const float scale = 1.0f / 262144.0f;
    size_t obase = (((size_t)b) << 23) + (nxy << 6) + nz;
    #pragma unroll
    for (int k = 0; k < 8; k++) {
        int o = wq * 8 + k;
        const float2* mrow = ms + o * 8;                        // wave-uniform LDS
        float sp = mrow[0].x;
        #pragma unroll
        for (int kz = 1; kz < 8; kz++) {
            float2 m = mrow[kz];
            sp += 2.0f * (m.x * c7[kz] - m.y * s7[kz]);
        }
        float gv = gelu_exact(sp * scale + acc[k]);
        xout[obase + ((size_t)o << 18)] = f2bf(gv);
        ys[o * 68 + nz] = gv;
    }
    if (do_z) {
        __syncthreads();             // b1s region dead -> hr/hi may overwrite
        {
            int o = t >> 3, q = t & 7;
            float h[8];
            #pragma unroll
            for (int p = 0; p < 8; p++) h[p] = ys[o * 68 + 8 * p + q];
            rdft8(h, hr, hi, t);
        }
        __syncthreads();
        {
            float2 r = zdft_combine(hr, hi, cosT, sinT, t >> 3, t & 7);
            a1[((size_t)(b * 4096 + nxy)) * 256 + t] = r;
        }
    }
}

// ---------------- projection (bf16 x input) ----------------
__global__ void k_proj(const unsigned short* __restrict__ x4, const float* __restrict__ w1,
                       const float* __restrict__ b1, const float* __restrict__ w2,
                       const float* __restrict__ b2, const float* __restrict__ state_in,
                       float* __restrict__ out) {
    int t = threadIdx.x;
    int g = blockIdx.x * 256 + t;
    int b = rfl(g >> 18);
    int n = g & (262144 - 1);
    float xv[32];
    const unsigned short* xb = x4 + (((size_t)b) << 23) + n;
    #pragma unroll 8
    for (int i = 0; i < 32; i++) xv[i] = bf2f(xb[(size_t)i << 18]);
    float h[32];
    for (int o = 0; o < 32; o++) {
        float a = b1[o];
        const float* w = w1 + o * 32;
        #pragma unroll
        for (int i = 0; i < 32; i++) a += w[i] * xv[i];
        h[o] = gelu_exact(a);
    }
    size_t base = ((size_t)b * 262144 + n) * 4;
    float4 sv = *(const float4*)(state_in + base);
    float r[4];
    for (int j = 0; j < 4; j++) {
        float a = b2[j];
        const float* w = w2 + j * 32;
        #pragma unroll
        for (int o = 0; o < 32; o++) a += w[o] * h[o];
        r[j] = a;
    }
    *(float4*)(out + base) = make_float4(sv.x + 0.05f * r[0], sv.y + 0.05f * r[1],
                                         sv.z + 0.05f * r[2], sv.w + 0.05f * r[3]);
}

extern "C" void kernel_launch(void* const* d_in, const int* in_sizes, int n_in,
                              void* d_out, int out_size, void* d_ws, size_t ws_size,
                              hipStream_t stream) {
    const float* state_in   = (const float*)d_in[0];
    const float* node_pos   = (const float*)d_in[1];
    const float* time_i     = (const float*)d_in[3];
    const float* conditions = (const float*)d_in[4];
    const float* t_embed_w  = (const float*)d_in[5];
    const float* t_embed_b  = (const float*)d_in[6];
    const float* c_embed_w  = (const float*)d_in[7];
    const float* c_embed_b  = (const float*)d_in[8];
    const float* lift_w     = (const float*)d_in[9];
    const float* lift_b     = (const float*)d_in[10];
    const float* spec_wr    = (const float*)d_in[11];
    const float* spec_wi    = (const float*)d_in[12];
    const float* byp_w      = (const float*)d_in[13];
    const float* byp_b      = (const float*)d_in[14];
    const float* proj1_w    = (const float*)d_in[15];
    const float* proj1_b    = (const float*)d_in[16];
    const float* proj2_w    = (const float*)d_in[17];
    const float* proj2_b    = (const float*)d_in[18];
    float* out = (float*)d_out;
    float* ws  = (float*)d_ws;

    unsigned short* xA = (unsigned short*)ws;                    // 16777216 u16
    unsigned short* xB = (unsigned short*)(ws + 8388608);        // 16777216 u16
    float2* a1   = (float2*)(ws + 16777216);    // 2097152 f2 -> ends 20971520
    float2* a2p  = (float2*)(ws + 20971520);    // 524288 f2  -> ends 22020096
    float2* xft  = (float2*)(ws + 22020096);    // 32768 f2   -> ends 22085632
    float2* yftp = (float2*)(ws + 22085632);    // 65536 f2   -> ends 22216704
    float2* b1   = (float2*)(ws + 22216704);    // 262144 f2  -> ends 22740992
    float*  embk = ws + 22740992;               // 64
    float*  wtb  = ws + 22741056;               // 4096
    float*  wlT  = ws + 22745152;               // 1184

    k_emb<<<2, 256, 0, stream>>>(time_i, conditions, t_embed_w, t_embed_b,
                                 c_embed_w, c_embed_b, lift_b, embk);
    k_wt<<<21, 256, 0, stream>>>(byp_w, lift_w, wtb, wlT);
    k_lift<<<8192, 256, 0, stream>>>(state_in, node_pos, wlT, embk, xA, a1);

    for (int l = 0; l < 4; l++) {
        unsigned short* xin  = (l & 1) ? xB : xA;
        unsigned short* xout = (l & 1) ? xA : xB;
        const float* wrl = spec_wr + (size_t)l * 524288;
        const float* wil = spec_wi + (size_t)l * 524288;
        void* args[] = {(void*)&a1, (void*)&a2p, (void*)&xft, (void*)&yftp,
                        (void*)&b1, (void*)&wrl, (void*)&wil};
        hipError_t err = hipLaunchCooperativeKernel((const void*)k_spec, dim3(256),
                                                    dim3(256), args, 0, stream);
        if (err != hipSuccess) {
            k_p1<<<256, 256, 0, stream>>>(a1, a2p);
            k_p2<<<256, 256, 0, stream>>>(a2p, xft);
            k_p3<<<256, 256, 0, stream>>>(xft, wrl, wil, yftp);
            k_p4<<<256, 256, 0, stream>>>(yftp, b1);
        }
        k_fin<<<8192, 256, 0, stream>>>(xin, b1, wtb + l * 1024, byp_b + l * 32,
                                        xout, a1, (l < 3) ? 1 : 0);
    }

    k_proj<<<2048, 256, 0, stream>>>(xA, proj1_w, proj1_b, proj2_w, proj2_b, state_in, out);
}

// Round 8
// 489.880 us; speedup vs baseline: 1.9728x; 1.9728x over previous
//
#include <hip/hip_runtime.h>
#include <math.h>

#define PI_F 3.14159265358979323846f

__device__ __forceinline__ float gelu_exact(float v) {
    return 0.5f * v * (1.0f + erff(v * 0.70710678118654752f));
}
__device__ __forceinline__ int rfl(int x) { return __builtin_amdgcn_readfirstlane(x); }

__device__ __forceinline__ unsigned short f2bf(float f) {   // RNE fp32->bf16
    unsigned int u = __float_as_uint(f);
    u += 0x7fffu + ((u >> 16) & 1u);
    return (unsigned short)(u >> 16);
}
__device__ __forceinline__ float bf2f(unsigned short h) {
    return __uint_as_float(((unsigned int)h) << 16);
}

// XCD-locality swizzle for 8192-block grids (blk%8 -> XCD round-robin).
__device__ __forceinline__ void swz8k(int blk, int& b, int& nx, int& ny) {
    int x = blk & 7;
    int j = blk >> 3;
    int pair = x * 16 + (j >> 6);
    ny = j & 63;
    b = pair >> 6;
    nx = pair & 63;
}

// Radix-8 stage A: 8-pt real DFT; write layout [j][t] pitch 257 -> banks (j+t)%32 (2-way, free)
__device__ __forceinline__ void rdft8(const float h[8], float* __restrict__ hr,
                                      float* __restrict__ hi, int t) {
    const float s2 = 0.70710678118654752f;
    float e0 = h[0] + h[4], e1 = h[1] + h[5], e2 = h[2] + h[6], e3 = h[3] + h[7];
    float o0 = h[0] - h[4], o1 = h[1] - h[5], o2 = h[2] - h[6], o3 = h[3] - h[7];
    float ee = e0 + e2, eo = e1 + e3;
    float H0r = ee + eo, H4r = ee - eo;
    float H2r = e0 - e2, H2i = -(e1 - e3);
    float t13p = s2 * (o1 + o3), t13m = s2 * (o1 - o3);
    float H1r = o0 + t13m, H1i = -o2 - t13p;
    float H3r = o0 - t13m, H3i =  o2 - t13p;
    hr[0 * 257 + t] = H0r;  hi[0 * 257 + t] = 0.0f;
    hr[1 * 257 + t] = H1r;  hi[1 * 257 + t] = H1i;
    hr[2 * 257 + t] = H2r;  hi[2 * 257 + t] = H2i;
    hr[3 * 257 + t] = H3r;  hi[3 * 257 + t] = H3i;
    hr[4 * 257 + t] = H4r;  hi[4 * 257 + t] = 0.0f;
    hr[5 * 257 + t] = H3r;  hi[5 * 257 + t] = -H3i;
    hr[6 * 257 + t] = H2r;  hi[6 * 257 + t] = -H2i;
    hr[7 * 257 + t] = H1r;  hi[7 * 257 + t] = -H1i;
}

// Radix-8 stage B with LDS twiddle tables (kz*q < 64, broadcast reads)
__device__ __forceinline__ float2 zdft_combine(const float* __restrict__ hr,
                                               const float* __restrict__ hi,
                                               const float* __restrict__ cosT,
                                               const float* __restrict__ sinT,
                                               int o, int kz) {
    float re = 0.0f, im = 0.0f;
    int base = kz * 257 + o * 8;
    #pragma unroll
    for (int q = 0; q < 8; q++) {
        float Hr = hr[base + q], Hi = hi[base + q];
        int m = (kz * q) & 63;
        float c = cosT[m], s = sinT[m];
        re += Hr * c + Hi * s;          // H * e^{-i kz q pi/32}
        im += Hi * c - Hr * s;
    }
    return make_float2(re, im);
}

// ---------------- emb ----------------
__global__ void k_emb(const float* __restrict__ time_i, const float* __restrict__ conditions,
                      const float* __restrict__ t_embed_w, const float* __restrict__ t_embed_b,
                      const float* __restrict__ c_embed_w, const float* __restrict__ c_embed_b,
                      const float* __restrict__ lift_b, float* __restrict__ embk) {
    __shared__ float red[8][32];
    int t = threadIdx.x;
    int b = blockIdx.x;
    int c = t & 31, lg = t >> 5;
    float acc = 0.0f;
    if (lg == 0) {
        acc = t_embed_b[c] + c_embed_b[c] + lift_b[c];
        float tv = time_i[b];
        float ang = PI_F * tv;
        const float* tw = t_embed_w + c * 11;
        for (int i = 0; i < 5; i++) {
            float s, co; sincosf(ang, &s, &co);
            acc += co * tw[i] + s * tw[5 + i];
            ang *= 2.0f;
        }
        acc += tv * tw[10];
    }
    const float* cw = c_embed_w + c * 352;
    for (int j = 0; j < 4; j++) {
        int l = lg * 4 + j;
        float v = conditions[b * 32 + l];
        float ang = PI_F * v;
        for (int i = 0; i < 5; i++) {
            float s, co; sincosf(ang, &s, &co);
            acc += co * cw[l * 10 + i] + s * cw[l * 10 + 5 + i];
            ang *= 2.0f;
        }
        acc += v * cw[320 + l];
    }
    red[lg][c] = acc;
    __syncthreads();
    if (t < 32) {
        float s = 0.0f;
        for (int g = 0; g < 8; g++) s += red[g][t];
        embk[b * 32 + t] = s;
    }
}

// -------- k_wt: transposed byp + lift weights --------
__global__ void k_wt(const float* __restrict__ byp_w, const float* __restrict__ lift_w,
                     float* __restrict__ wtb, float* __restrict__ wlT) {
    int idx = blockIdx.x * 256 + threadIdx.x;
    if (idx < 4096) {
        int l = idx >> 10, rem = idx & 1023;
        int o = rem >> 5, i = rem & 31;
        wtb[(l << 10) + (i << 5) + o] = byp_w[idx];
    } else if (idx < 4096 + 1184) {
        int j = idx - 4096;
        int q = j >> 5, o = j & 31;
        wlT[j] = lift_w[o * 37 + q];
    }
}

// ------- k_lift: lift conv + emb, radix-8 forward z-DFT. x0 in bf16. -------
__global__ __launch_bounds__(256) void k_lift(const float* __restrict__ state_in,
        const float* __restrict__ node_pos, const float* __restrict__ wlT,
        const float* __restrict__ embk, unsigned short* __restrict__ x0,
        float2* __restrict__ a1) {
    __shared__ __align__(16) float S[8784];
    float* fs   = S;             // 2368 [q][nz]
    float* ys   = S + 2368;      // 2176 [o][nz] pitch 68
    float* hr   = S + 4544;      // 2056 [j][t] pitch 257
    float* hi   = S + 6600;      // 2056
    float* cosT = S + 8656;      // 64
    float* sinT = S + 8720;      // 64
    int t = threadIdx.x;
    int b, nx, ny; swz8k(blockIdx.x, b, nx, ny);
    int nxy = nx * 64 + ny;

    if (t < 64) { float s, c; sincosf((float)t * (PI_F / 32.0f), &s, &c); cosT[t] = c; sinT[t] = s; }
    if (t >= 64 && t < 128) {
        int tt = t - 64;
        int n = (nxy << 6) + tt;
        const float4 s4 = *(const float4*)(state_in + ((size_t)b * 262144 + n) * 4);
        fs[0 * 64 + tt] = s4.x; fs[1 * 64 + tt] = s4.y;
        fs[2 * 64 + tt] = s4.z; fs[3 * 64 + tt] = s4.w;
        const float* pp = node_pos + ((size_t)b * 262144 + n) * 3;
        for (int l = 0; l < 3; l++) {
            float p = pp[l];
            float ang = PI_F * p;
            for (int i = 0; i < 5; i++) {
                float s, co; sincosf(ang, &s, &co);
                fs[(4 + l * 10 + i) * 64 + tt] = co;
                fs[(4 + l * 10 + 5 + i) * 64 + tt] = s;
                ang *= 2.0f;
            }
            fs[(34 + l) * 64 + tt] = p;
        }
    }
    __syncthreads();

    int nz = t & 63;
    int wq = rfl(t >> 6);
    float acc[8];
    #pragma unroll
    for (int k = 0; k < 8; k++) acc[k] = embk[b * 32 + wq * 8 + k];
    #pragma unroll
    for (int q = 0; q < 37; q++) {
        float fq = fs[q * 64 + nz];
        const float* w = wlT + q * 32 + wq * 8;
        #pragma unroll
        for (int k = 0; k < 8; k++) acc[k] += w[k] * fq;
    }
    int n = (nxy << 6) + nz;
    #pragma unroll
    for (int k = 0; k < 8; k++) {
        int o = wq * 8 + k;
        x0[(((size_t)(b * 32 + o)) << 18) + n] = f2bf(acc[k]);
        ys[o * 68 + nz] = acc[k];
    }
    __syncthreads();
    {   // stage A
        int o = t >> 3, q = t & 7;
        float h[8];
        #pragma unroll
        for (int p = 0; p < 8; p++) h[p] = ys[o * 68 + 8 * p + q];
        rdft8(h, hr, hi, t);
    }
    __syncthreads();
    {   // stage B
        float2 r = zdft_combine(hr, hi, cosT, sinT, t >> 3, t & 7);
        a1[((size_t)(b * 4096 + nxy)) * 256 + t] = r;
    }
}

// =================== spectral mid-section: 4 phase kernels ===================

// k_p1: forward y-DFT partials over ny-halves. a1 -> a2p[half][pair][jj][ky]
__global__ __launch_bounds__(256) void k_p1(const float2* __restrict__ a1,
                                            float2* __restrict__ a2p) {
    int blk = blockIdx.x, t = threadIdx.x;
    int x = blk & 7, r = blk >> 3;
    int pair = x * 16 + (r & 15);
    int half = r >> 4;
    const float2* src = a1 + ((size_t)(pair * 64 + half * 32)) * 256 + t;
    float accr[8], acci[8];
    #pragma unroll
    for (int k = 0; k < 8; k++) { accr[k] = 0.0f; acci[k] = 0.0f; }
    const float bc = 0.99518472667f;          // cos(pi/32)
    const float bs = -0.09801714033f;         // -sin(pi/32)
    float wc = half ? -1.0f : 1.0f;           // e^{-i*32*pi/32} = -1
    float ws = 0.0f;
    #pragma unroll 4
    for (int j = 0; j < 32; j++) {
        float2 v = src[(size_t)j * 256];
        accr[0] += v.x; acci[0] += v.y;
        float tc = wc, ts = ws;
        #pragma unroll
        for (int ky = 1; ky < 8; ky++) {
            accr[ky] += v.x * tc - v.y * ts;
            acci[ky] += v.x * ts + v.y * tc;
            float nt = tc * wc - ts * ws; ts = ts * wc + tc * ws; tc = nt;
        }
        float nw = wc * bc - ws * bs; ws = ws * bc + wc * bs; wc = nw;
    }
    float4* dst = (float4*)(a2p + (size_t)half * 262144 + ((size_t)(pair * 256 + t)) * 8);
    #pragma unroll
    for (int j = 0; j < 4; j++)
        dst[j] = make_float4(accr[2 * j], acci[2 * j], accr[2 * j + 1], acci[2 * j + 1]);
}

// k_p2: forward x-DFT (sums partials). -> xft[((b*32+c)*8+kz)*64 + ky*8+kx]
__global__ __launch_bounds__(256) void k_p2(const float2* __restrict__ a2p,
                                            float2* __restrict__ xft) {
    __shared__ __align__(16) float2 SH[1040];
    int blk = blockIdx.x, t = threadIdx.x;
    for (int lu = 0; lu < 2; lu++) {
        int un = blk * 2 + lu;
        int b = un >> 8, ckz = un & 255;
        size_t base = (size_t)b * 131072 + (size_t)ckz * 8;
        for (int e = t; e < 512; e += 256) {
            size_t a = base + (size_t)(e >> 3) * 2048 + (e & 7);
            float2 v0 = a2p[a];
            float2 v1 = a2p[a + 262144];
            SH[lu * 520 + e] = make_float2(v0.x + v1.x, v0.y + v1.y);
        }
    }
    __syncthreads();
    if (t < 128) {
        int lu = t >> 6, out = t & 63;
        int un = blk * 2 + lu;
        int kx = out & 7;
        float sn, cc; sincosf((float)kx * (PI_F / 32.0f), &sn, &cc);
        float bsn = -sn;
        float tc = 1.0f, ts = 0.0f, rr = 0.0f, ri = 0.0f;
        const float2* row = SH + lu * 520 + (out >> 3);
        for (int nx = 0; nx < 64; nx++) {
            float2 v = row[nx * 8];
            rr += v.x * tc - v.y * ts;
            ri += v.x * ts + v.y * tc;
            float nt = tc * cc - ts * bsn; ts = ts * cc + tc * bsn; tc = nt;
        }
        xft[(size_t)un * 64 + out] = make_float2(rr, ri);
    }
}

// k_p3: mode mix over i-halves. -> yftp[ih][((b*32+o)*8+kz)*64 + ky*8+kx]
__global__ __launch_bounds__(256) void k_p3(const float2* __restrict__ xft,
        const float* __restrict__ wr, const float* __restrict__ wi,
        float2* __restrict__ yftp) {
    __shared__ __align__(16) float2 SH[128];
    int blk = blockIdx.x, t = threadIdx.x;
    int unit = blk >> 1, ih = blk & 1;
    int b = unit >> 6, kx = (unit >> 3) & 7, ky = unit & 7;
    if (t < 128) {
        int il = t >> 3, kz = t & 7;
        int i = ih * 16 + il;
        SH[t] = xft[((size_t)((b * 32 + i) * 8 + kz)) * 64 + ky * 8 + kx];
    }
    __syncthreads();
    int o = t >> 3, kz = t & 7;
    float yr = 0.0f, yi = 0.0f;
    for (int il = 0; il < 16; il++) {
        int i = ih * 16 + il;
        float2 xv = SH[il * 8 + kz];
        int wofs = ((i * 32 + o) << 9) + kx * 64 + ky * 8 + kz;
        float wrv = wr[wofs], wiv = wi[wofs];
        yr += xv.x * wrv - xv.y * wiv;
        yi += xv.x * wiv + xv.y * wrv;
    }
    yftp[(size_t)ih * 32768 + ((size_t)((b * 32 + o) * 8 + kz)) * 64 + ky * 8 + kx]
        = make_float2(yr, yi);
}

// k_p4: inverse x (sums yftp halves). -> b1[b][nx][o*8+kz][ky]
__global__ __launch_bounds__(256) void k_p4(const float2* __restrict__ yftp,
                                            float2* __restrict__ b1) {
    __shared__ __align__(16) float2 SH[4608];
    int blk = blockIdx.x, t = threadIdx.x;
    for (int u = 0; u < 2; u++) {
        if (u) __syncthreads();
        int unit = blk * 2 + u;
        int b = unit >> 8, nx = (unit >> 2) & 63, og = unit & 3;
        size_t sbase = ((size_t)(b * 32 + og * 8)) * 512;
        for (int e = t; e < 4096; e += 256) {
            float2 v0 = yftp[sbase + e];
            float2 v1 = yftp[32768 + sbase + e];
            SH[(e >> 3) * 9 + (e & 7)] = make_float2(v0.x + v1.x, v0.y + v1.y);
        }
        __syncthreads();
        float cs, ss; sincosf((float)nx * (PI_F / 32.0f), &ss, &cs);
        float2* dst = b1 + ((size_t)(b * 64 + nx)) * 2048 + og * 512;
        for (int h = 0; h < 2; h++) {
            int idx = h * 256 + t;
            const float2* row = SH + idx * 9;
            float c = 1.0f, s = 0.0f, rr = 0.0f, ri = 0.0f;
            #pragma unroll
            for (int kx = 0; kx < 8; kx++) {
                float2 y = row[kx];
                rr += y.x * c - y.y * s;      // e^{+i kx nx θ}
                ri += y.x * s + y.y * c;
                float nc = c * cs - s * ss; s = s * cs + c * ss; c = nc;
            }
            dst[idx] = make_float2(rr, ri);
        }
    }
}

// ------- k_fin: inverse-y + bypass (bf16 x) + inverse-z + gelu + radix-8 fwd z -------
__global__ __launch_bounds__(256) void k_fin(
        const unsigned short* __restrict__ xin, const float2* __restrict__ b1,
        const float* __restrict__ wt, const float* __restrict__ bb,
        unsigned short* __restrict__ xout, float2* __restrict__ a1, int do_z) {
    __shared__ __align__(16) float S[8080];
    float* b1sr = S;                              // 2112 (dead after inv-y)
    float* b1si = S + 2112;                       // 2112
    float* hr   = S;                              // 2056 alias
    float* hi   = S + 2112;                       // 2056 alias
    unsigned short* xsu = (unsigned short*)(S + 4224);   // 2048 u16
    float2* ms  = (float2*)(S + 5248);            // 256 f2
    float* ys   = S + 5760;                       // 2176 pitch 68
    float2* twy = (float2*)(S + 7936);            // 8 f2
    float* cosT = S + 7952;                       // 64
    float* sinT = S + 8016;                       // 64
    int t = threadIdx.x;
    int b, nx, ny; swz8k(blockIdx.x, b, nx, ny);
    int nxy = nx * 64 + ny;

    if (t < 64) { float s, c; sincosf((float)t * (PI_F / 32.0f), &s, &c); cosT[t] = c; sinT[t] = s; }
    if (t >= 64 && t < 72) {
        int ky = t - 64;
        float s, c; sincosf((float)((ky * ny) & 63) * (PI_F / 32.0f), &s, &c);
        twy[ky] = make_float2(c, s);
    }
    {   // stage x (bf16): one uint4 (8 elems) per thread
        int ch = t >> 3, q = t & 7;
        uint4 v = *(const uint4*)(xin + (((size_t)b) << 23) + (nxy << 6)
                                  + ((size_t)ch << 18) + q * 8);
        *(uint4*)(xsu + ch * 64 + q * 8) = v;
    }
    const float2* bsrc = b1 + ((size_t)(b * 64 + nx)) * 2048;   // contiguous 16 KB
    for (int u = 0; u < 8; u++) {
        int g = u * 256 + t;
        float2 v = bsrc[g];
        int ky = g & 7, okz = g >> 3;
        b1sr[ky * 264 + okz] = v.x;
        b1si[ky * 264 + okz] = v.y;
    }
    __syncthreads();
    {   // inverse-y with block-uniform twiddles
        float mr = 0.0f, mi = 0.0f;
        #pragma unroll
        for (int ky = 0; ky < 8; ky++) {
            float vr = b1sr[ky * 264 + t], vi = b1si[ky * 264 + t];
            float2 w = twy[ky];
            mr += vr * w.x - vi * w.y;        // e^{+i ky ny θ}
            mi += vr * w.y + vi * w.x;
        }
        ms[t] = make_float2(mr, mi);
    }
    __syncthreads();

    int nz = t & 63;
    int wq = rfl(t >> 6);
    float c7[8], s7[8];
    c7[0] = 1.f; s7[0] = 0.f;
    {
        float cs = cosT[nz], ss = sinT[nz];
        #pragma unroll
        for (int kz = 1; kz < 8; kz++) {
            c7[kz] = c7[kz - 1] * cs - s7[kz - 1] * ss;
            s7[kz] = s7[kz - 1] * cs + c7[kz - 1] * ss;
        }
    }
    float acc[8];
    #pragma unroll
    for (int k = 0; k < 8; k++) acc[k] = bb[wq * 8 + k];        // s_load
    #pragma unroll 8
    for (int i = 0; i < 32; i++) {
        float xv = bf2f(xsu[i * 64 + nz]);                      // paired ds_read_u16
        const float* wrow = wt + i * 32 + wq * 8;               // s_load_dwordx8
        #pragma unroll
        for (int k = 0; k < 8; k++) acc[k] += wrow[k] * xv;
    }
    const float scale = 1.0f / 262144.0f;
    size_t obase = (((size_t)b) << 23) + (nxy << 6) + nz;
    #pragma unroll
    for (int k = 0; k < 8; k++) {
        int o = wq * 8 + k;
        const float2* mrow = ms + o * 8;                        // wave-uniform LDS
        float sp = mrow[0].x;
        #pragma unroll
        for (int kz = 1; kz < 8; kz++) {
            float2 m = mrow[kz];
            sp += 2.0f * (m.x * c7[kz] - m.y * s7[kz]);
        }
        float gv = gelu_exact(sp * scale + acc[k]);
        xout[obase + ((size_t)o << 18)] = f2bf(gv);
        ys[o * 68 + nz] = gv;
    }
    if (do_z) {
        __syncthreads();             // b1s region dead -> hr/hi may overwrite
        {
            int o = t >> 3, q = t & 7;
            float h[8];
            #pragma unroll
            for (int p = 0; p < 8; p++) h[p] = ys[o * 68 + 8 * p + q];
            rdft8(h, hr, hi, t);
        }
        __syncthreads();
        {
            float2 r = zdft_combine(hr, hi, cosT, sinT, t >> 3, t & 7);
            a1[((size_t)(b * 4096 + nxy)) * 256 + t] = r;
        }
    }
}

// ---------------- projection (bf16 x input) ----------------
__global__ void k_proj(const unsigned short* __restrict__ x4, const float* __restrict__ w1,
                       const float* __restrict__ b1, const float* __restrict__ w2,
                       const float* __restrict__ b2, const float* __restrict__ state_in,
                       float* __restrict__ out) {
    int t = threadIdx.x;
    int g = blockIdx.x * 256 + t;
    int b = rfl(g >> 18);
    int n = g & (262144 - 1);
    float xv[32];
    const unsigned short* xb = x4 + (((size_t)b) << 23) + n;
    #pragma unroll 8
    for (int i = 0; i < 32; i++) xv[i] = bf2f(xb[(size_t)i << 18]);
    float h[32];
    for (int o = 0; o < 32; o++) {
        float a = b1[o];
        const float* w = w1 + o * 32;
        #pragma unroll
        for (int i = 0; i < 32; i++) a += w[i] * xv[i];
        h[o] = gelu_exact(a);
    }
    size_t base = ((size_t)b * 262144 + n) * 4;
    float4 sv = *(const float4*)(state_in + base);
    float r[4];
    for (int j = 0; j < 4; j++) {
        float a = b2[j];
        const float* w = w2 + j * 32;
        #pragma unroll
        for (int o = 0; o < 32; o++) a += w[o] * h[o];
        r[j] = a;
    }
    *(float4*)(out + base) = make_float4(sv.x + 0.05f * r[0], sv.y + 0.05f * r[1],
                                         sv.z + 0.05f * r[2], sv.w + 0.05f * r[3]);
}

extern "C" void kernel_launch(void* const* d_in, const int* in_sizes, int n_in,
                              void* d_out, int out_size, void* d_ws, size_t ws_size,
                              hipStream_t stream) {
    const float* state_in   = (const float*)d_in[0];
    const float* node_pos   = (const float*)d_in[1];
    const float* time_i     = (const float*)d_in[3];
    const float* conditions = (const float*)d_in[4];
    const float* t_embed_w  = (const float*)d_in[5];
    const float* t_embed_b  = (const float*)d_in[6];
    const float* c_embed_w  = (const float*)d_in[7];
    const float* c_embed_b  = (const float*)d_in[8];
    const float* lift_w     = (const float*)d_in[9];
    const float* lift_b     = (const float*)d_in[10];
    const float* spec_wr    = (const float*)d_in[11];
    const float* spec_wi    = (const float*)d_in[12];
    const float* byp_w      = (const float*)d_in[13];
    const float* byp_b      = (const float*)d_in[14];
    const float* proj1_w    = (const float*)d_in[15];
    const float* proj1_b    = (const float*)d_in[16];
    const float* proj2_w    = (const float*)d_in[17];
    const float* proj2_b    = (const float*)d_in[18];
    float* out = (float*)d_out;
    float* ws  = (float*)d_ws;

    unsigned short* xA = (unsigned short*)ws;                    // 16777216 u16
    unsigned short* xB = (unsigned short*)(ws + 8388608);        // 16777216 u16
    float2* a1   = (float2*)(ws + 16777216);    // 2097152 f2 -> ends 20971520
    float2* a2p  = (float2*)(ws + 20971520);    // 524288 f2  -> ends 22020096
    float2* xft  = (float2*)(ws + 22020096);    // 32768 f2   -> ends 22085632
    float2* yftp = (float2*)(ws + 22085632);    // 65536 f2   -> ends 22216704
    float2* b1   = (float2*)(ws + 22216704);    // 262144 f2  -> ends 22740992
    float*  embk = ws + 22740992;               // 64
    float*  wtb  = ws + 22741056;               // 4096
    float*  wlT  = ws + 22745152;               // 1184

    k_emb<<<2, 256, 0, stream>>>(time_i, conditions, t_embed_w, t_embed_b,
                                 c_embed_w, c_embed_b, lift_b, embk);
    k_wt<<<21, 256, 0, stream>>>(byp_w, lift_w, wtb, wlT);
    k_lift<<<8192, 256, 0, stream>>>(state_in, node_pos, wlT, embk, xA, a1);

    for (int l = 0; l < 4; l++) {
        unsigned short* xin  = (l & 1) ? xB : xA;
        unsigned short* xout = (l & 1) ? xA : xB;
        const float* wrl = spec_wr + (size_t)l * 524288;
        const float* wil = spec_wi + (size_t)l * 524288;
        k_p1<<<256, 256, 0, stream>>>(a1, a2p);
        k_p2<<<256, 256, 0, stream>>>(a2p, xft);
        k_p3<<<256, 256, 0, stream>>>(xft, wrl, wil, yftp);
        k_p4<<<256, 256, 0, stream>>>(yftp, b1);
        k_fin<<<8192, 256, 0, stream>>>(xin, b1, wtb + l * 1024, byp_b + l * 32,
                                        xout, a1, (l < 3) ? 1 : 0);
    }

    k_proj<<<2048, 256, 0, stream>>>(xA, proj1_w, proj1_b, proj2_w, proj2_b, state_in, out);
}

// Round 9
// 474.455 us; speedup vs baseline: 2.0370x; 1.0325x over previous
//
#include <hip/hip_runtime.h>
#include <math.h>

#define PI_F 3.14159265358979323846f

typedef __bf16 bf16x8 __attribute__((ext_vector_type(8)));
typedef float floatx4 __attribute__((ext_vector_type(4)));
union U8 { unsigned short u[8]; bf16x8 v; };

__device__ __forceinline__ float gelu_exact(float v) {
    return 0.5f * v * (1.0f + erff(v * 0.70710678118654752f));
}
__device__ __forceinline__ int rfl(int x) { return __builtin_amdgcn_readfirstlane(x); }

__device__ __forceinline__ unsigned short f2bf(float f) {   // RNE fp32->bf16
    unsigned int u = __float_as_uint(f);
    u += 0x7fffu + ((u >> 16) & 1u);
    return (unsigned short)(u >> 16);
}
__device__ __forceinline__ float bf2f(unsigned short h) {
    return __uint_as_float(((unsigned int)h) << 16);
}

// XCD-locality swizzle for 8192-block grids (blk%8 -> XCD round-robin).
__device__ __forceinline__ void swz8k(int blk, int& b, int& nx, int& ny) {
    int x = blk & 7;
    int j = blk >> 3;
    int pair = x * 16 + (j >> 6);
    ny = j & 63;
    b = pair >> 6;
    nx = pair & 63;
}

// Radix-8 stage A: 8-pt real DFT; write layout [j][t] pitch 257 -> banks (j+t)%32 (2-way, free)
__device__ __forceinline__ void rdft8(const float h[8], float* __restrict__ hr,
                                      float* __restrict__ hi, int t) {
    const float s2 = 0.70710678118654752f;
    float e0 = h[0] + h[4], e1 = h[1] + h[5], e2 = h[2] + h[6], e3 = h[3] + h[7];
    float o0 = h[0] - h[4], o1 = h[1] - h[5], o2 = h[2] - h[6], o3 = h[3] - h[7];
    float ee = e0 + e2, eo = e1 + e3;
    float H0r = ee + eo, H4r = ee - eo;
    float H2r = e0 - e2, H2i = -(e1 - e3);
    float t13p = s2 * (o1 + o3), t13m = s2 * (o1 - o3);
    float H1r = o0 + t13m, H1i = -o2 - t13p;
    float H3r = o0 - t13m, H3i =  o2 - t13p;
    hr[0 * 257 + t] = H0r;  hi[0 * 257 + t] = 0.0f;
    hr[1 * 257 + t] = H1r;  hi[1 * 257 + t] = H1i;
    hr[2 * 257 + t] = H2r;  hi[2 * 257 + t] = H2i;
    hr[3 * 257 + t] = H3r;  hi[3 * 257 + t] = H3i;
    hr[4 * 257 + t] = H4r;  hi[4 * 257 + t] = 0.0f;
    hr[5 * 257 + t] = H3r;  hi[5 * 257 + t] = -H3i;
    hr[6 * 257 + t] = H2r;  hi[6 * 257 + t] = -H2i;
    hr[7 * 257 + t] = H1r;  hi[7 * 257 + t] = -H1i;
}

// Radix-8 stage B with LDS twiddle tables
__device__ __forceinline__ float2 zdft_combine(const float* __restrict__ hr,
                                               const float* __restrict__ hi,
                                               const float* __restrict__ cosT,
                                               const float* __restrict__ sinT,
                                               int o, int kz) {
    float re = 0.0f, im = 0.0f;
    int base = kz * 257 + o * 8;
    #pragma unroll
    for (int q = 0; q < 8; q++) {
        float Hr = hr[base + q], Hi = hi[base + q];
        int m = (kz * q) & 63;
        float c = cosT[m], s = sinT[m];
        re += Hr * c + Hi * s;          // H * e^{-i kz q pi/32}
        im += Hi * c - Hr * s;
    }
    return make_float2(re, im);
}

// ---------------- emb ----------------
__global__ void k_emb(const float* __restrict__ time_i, const float* __restrict__ conditions,
                      const float* __restrict__ t_embed_w, const float* __restrict__ t_embed_b,
                      const float* __restrict__ c_embed_w, const float* __restrict__ c_embed_b,
                      const float* __restrict__ lift_b, float* __restrict__ embk) {
    __shared__ float red[8][32];
    int t = threadIdx.x;
    int b = blockIdx.x;
    int c = t & 31, lg = t >> 5;
    float acc = 0.0f;
    if (lg == 0) {
        acc = t_embed_b[c] + c_embed_b[c] + lift_b[c];
        float tv = time_i[b];
        float ang = PI_F * tv;
        const float* tw = t_embed_w + c * 11;
        for (int i = 0; i < 5; i++) {
            float s, co; sincosf(ang, &s, &co);
            acc += co * tw[i] + s * tw[5 + i];
            ang *= 2.0f;
        }
        acc += tv * tw[10];
    }
    const float* cw = c_embed_w + c * 352;
    for (int j = 0; j < 4; j++) {
        int l = lg * 4 + j;
        float v = conditions[b * 32 + l];
        float ang = PI_F * v;
        for (int i = 0; i < 5; i++) {
            float s, co; sincosf(ang, &s, &co);
            acc += co * cw[l * 10 + i] + s * cw[l * 10 + 5 + i];
            ang *= 2.0f;
        }
        acc += v * cw[320 + l];
    }
    red[lg][c] = acc;
    __syncthreads();
    if (t < 32) {
        float s = 0.0f;
        for (int g = 0; g < 8; g++) s += red[g][t];
        embk[b * 32 + t] = s;
    }
}

// -------- k_wt: bf16 bypass weights [l][o][i] + transposed lift weights --------
__global__ void k_wt(const float* __restrict__ byp_w, const float* __restrict__ lift_w,
                     unsigned short* __restrict__ wbh, float* __restrict__ wlT) {
    int idx = blockIdx.x * 256 + threadIdx.x;
    if (idx < 4096) {
        wbh[idx] = f2bf(byp_w[idx]);          // same [l][o][i] order (A-fragment layout)
    } else if (idx < 4096 + 1184) {
        int j = idx - 4096;
        int q = j >> 5, o = j & 31;
        wlT[j] = lift_w[o * 37 + q];
    }
}

// ------- k_lift: lift conv + emb, radix-8 forward z-DFT. x0 in bf16. -------
__global__ __launch_bounds__(256) void k_lift(const float* __restrict__ state_in,
        const float* __restrict__ node_pos, const float* __restrict__ wlT,
        const float* __restrict__ embk, unsigned short* __restrict__ x0,
        float2* __restrict__ a1) {
    __shared__ __align__(16) float S[8784];
    float* fs   = S;             // 2368 [q][nz]
    float* ys   = S + 2368;      // 2176 [o][nz] pitch 68
    float* hr   = S + 4544;      // 2056 [j][t] pitch 257
    float* hi   = S + 6600;      // 2056
    float* cosT = S + 8656;      // 64
    float* sinT = S + 8720;      // 64
    int t = threadIdx.x;
    int b, nx, ny; swz8k(blockIdx.x, b, nx, ny);
    int nxy = nx * 64 + ny;

    if (t < 64) { float s, c; sincosf((float)t * (PI_F / 32.0f), &s, &c); cosT[t] = c; sinT[t] = s; }
    if (t < 192) {
        // t = nz*3 + l : coalesced node_pos read, one sincosf + 4 exact doublings
        int nzf = t / 3;
        int l = t - nzf * 3;
        float p = node_pos[((size_t)b * 262144 + (nxy << 6)) * 3 + t];
        float s, c; sincosf(PI_F * p, &s, &c);
        #pragma unroll
        for (int i = 0; i < 5; i++) {
            fs[(4 + l * 10 + i) * 64 + nzf] = c;
            fs[(4 + l * 10 + 5 + i) * 64 + nzf] = s;
            float nc = 2.0f * c * c - 1.0f;
            s = 2.0f * s * c;
            c = nc;
        }
        fs[(34 + l) * 64 + nzf] = p;
    } else {
        int nzf = t - 192;
        const float4 s4 = *(const float4*)(state_in + ((size_t)b * 262144 + (nxy << 6) + nzf) * 4);
        fs[0 * 64 + nzf] = s4.x; fs[1 * 64 + nzf] = s4.y;
        fs[2 * 64 + nzf] = s4.z; fs[3 * 64 + nzf] = s4.w;
    }
    __syncthreads();

    int nz = t & 63;
    int wq = rfl(t >> 6);
    float acc[8];
    #pragma unroll
    for (int k = 0; k < 8; k++) acc[k] = embk[b * 32 + wq * 8 + k];
    #pragma unroll
    for (int q = 0; q < 37; q++) {
        float fq = fs[q * 64 + nz];
        const float* w = wlT + q * 32 + wq * 8;
        #pragma unroll
        for (int k = 0; k < 8; k++) acc[k] += w[k] * fq;
    }
    int n = (nxy << 6) + nz;
    #pragma unroll
    for (int k = 0; k < 8; k++) {
        int o = wq * 8 + k;
        x0[(((size_t)(b * 32 + o)) << 18) + n] = f2bf(acc[k]);
        ys[o * 68 + nz] = acc[k];
    }
    __syncthreads();
    {   // stage A
        int o = t >> 3, q = t & 7;
        float h[8];
        #pragma unroll
        for (int p = 0; p < 8; p++) h[p] = ys[o * 68 + 8 * p + q];
        rdft8(h, hr, hi, t);
    }
    __syncthreads();
    {   // stage B
        float2 r = zdft_combine(hr, hi, cosT, sinT, t >> 3, t & 7);
        a1[((size_t)(b * 4096 + nxy)) * 256 + t] = r;
    }
}

// =================== spectral mid-section: 4 phase kernels ===================

__global__ __launch_bounds__(256) void k_p1(const float2* __restrict__ a1,
                                            float2* __restrict__ a2p) {
    int blk = blockIdx.x, t = threadIdx.x;
    int x = blk & 7, r = blk >> 3;
    int pair = x * 16 + (r & 15);
    int half = r >> 4;
    const float2* src = a1 + ((size_t)(pair * 64 + half * 32)) * 256 + t;
    float accr[8], acci[8];
    #pragma unroll
    for (int k = 0; k < 8; k++) { accr[k] = 0.0f; acci[k] = 0.0f; }
    const float bc = 0.99518472667f;
    const float bs = -0.09801714033f;
    float wc = half ? -1.0f : 1.0f;
    float ws = 0.0f;
    #pragma unroll 4
    for (int j = 0; j < 32; j++) {
        float2 v = src[(size_t)j * 256];
        accr[0] += v.x; acci[0] += v.y;
        float tc = wc, ts = ws;
        #pragma unroll
        for (int ky = 1; ky < 8; ky++) {
            accr[ky] += v.x * tc - v.y * ts;
            acci[ky] += v.x * ts + v.y * tc;
            float nt = tc * wc - ts * ws; ts = ts * wc + tc * ws; tc = nt;
        }
        float nw = wc * bc - ws * bs; ws = ws * bc + wc * bs; wc = nw;
    }
    float4* dst = (float4*)(a2p + (size_t)half * 262144 + ((size_t)(pair * 256 + t)) * 8);
    #pragma unroll
    for (int j = 0; j < 4; j++)
        dst[j] = make_float4(accr[2 * j], acci[2 * j], accr[2 * j + 1], acci[2 * j + 1]);
}

__global__ __launch_bounds__(256) void k_p2(const float2* __restrict__ a2p,
                                            float2* __restrict__ xft) {
    __shared__ __align__(16) float2 SH[1040];
    int blk = blockIdx.x, t = threadIdx.x;
    for (int lu = 0; lu < 2; lu++) {
        int un = blk * 2 + lu;
        int b = un >> 8, ckz = un & 255;
        size_t base = (size_t)b * 131072 + (size_t)ckz * 8;
        for (int e = t; e < 512; e += 256) {
            size_t a = base + (size_t)(e >> 3) * 2048 + (e & 7);
            float2 v0 = a2p[a];
            float2 v1 = a2p[a + 262144];
            SH[lu * 520 + e] = make_float2(v0.x + v1.x, v0.y + v1.y);
        }
    }
    __syncthreads();
    if (t < 128) {
        int lu = t >> 6, out = t & 63;
        int un = blk * 2 + lu;
        int kx = out & 7;
        float sn, cc; sincosf((float)kx * (PI_F / 32.0f), &sn, &cc);
        float bsn = -sn;
        float tc = 1.0f, ts = 0.0f, rr = 0.0f, ri = 0.0f;
        const float2* row = SH + lu * 520 + (out >> 3);
        for (int nx = 0; nx < 64; nx++) {
            float2 v = row[nx * 8];
            rr += v.x * tc - v.y * ts;
            ri += v.x * ts + v.y * tc;
            float nt = tc * cc - ts * bsn; ts = ts * cc + tc * bsn; tc = nt;
        }
        xft[(size_t)un * 64 + out] = make_float2(rr, ri);
    }
}

__global__ __launch_bounds__(256) void k_p3(const float2* __restrict__ xft,
        const float* __restrict__ wr, const float* __restrict__ wi,
        float2* __restrict__ yftp) {
    __shared__ __align__(16) float2 SH[128];
    int blk = blockIdx.x, t = threadIdx.x;
    int unit = blk >> 1, ih = blk & 1;
    int b = unit >> 6, kx = (unit >> 3) & 7, ky = unit & 7;
    if (t < 128) {
        int il = t >> 3, kz = t & 7;
        int i = ih * 16 + il;
        SH[t] = xft[((size_t)((b * 32 + i) * 8 + kz)) * 64 + ky * 8 + kx];
    }
    __syncthreads();
    int o = t >> 3, kz = t & 7;
    float yr = 0.0f, yi = 0.0f;
    for (int il = 0; il < 16; il++) {
        int i = ih * 16 + il;
        float2 xv = SH[il * 8 + kz];
        int wofs = ((i * 32 + o) << 9) + kx * 64 + ky * 8 + kz;
        float wrv = wr[wofs], wiv = wi[wofs];
        yr += xv.x * wrv - xv.y * wiv;
        yi += xv.x * wiv + xv.y * wrv;
    }
    yftp[(size_t)ih * 32768 + ((size_t)((b * 32 + o) * 8 + kz)) * 64 + ky * 8 + kx]
        = make_float2(yr, yi);
}

__global__ __launch_bounds__(256) void k_p4(const float2* __restrict__ yftp,
                                            float2* __restrict__ b1) {
    __shared__ __align__(16) float2 SH[4608];
    int blk = blockIdx.x, t = threadIdx.x;
    for (int u = 0; u < 2; u++) {
        if (u) __syncthreads();
        int unit = blk * 2 + u;
        int b = unit >> 8, nx = (unit >> 2) & 63, og = unit & 3;
        size_t sbase = ((size_t)(b * 32 + og * 8)) * 512;
        for (int e = t; e < 4096; e += 256) {
            float2 v0 = yftp[sbase + e];
            float2 v1 = yftp[32768 + sbase + e];
            SH[(e >> 3) * 9 + (e & 7)] = make_float2(v0.x + v1.x, v0.y + v1.y);
        }
        __syncthreads();
        float cs, ss; sincosf((float)nx * (PI_F / 32.0f), &ss, &cs);
        float2* dst = b1 + ((size_t)(b * 64 + nx)) * 2048 + og * 512;
        for (int h = 0; h < 2; h++) {
            int idx = h * 256 + t;
            const float2* row = SH + idx * 9;
            float c = 1.0f, s = 0.0f, rr = 0.0f, ri = 0.0f;
            #pragma unroll
            for (int kx = 0; kx < 8; kx++) {
                float2 y = row[kx];
                rr += y.x * c - y.y * s;
                ri += y.x * s + y.y * c;
                float nc = c * cs - s * ss; s = s * cs + c * ss; c = nc;
            }
            dst[idx] = make_float2(rr, ri);
        }
    }
}

// ------- k_fin: inverse-y + MFMA bypass (bf16) + inverse-z + gelu + radix-8 fwd z -------
__global__ __launch_bounds__(256) void k_fin(
        const unsigned short* __restrict__ xin, const float2* __restrict__ b1,
        const unsigned short* __restrict__ wbh, const float* __restrict__ bb,
        unsigned short* __restrict__ xout, float2* __restrict__ a1, int do_z) {
    __shared__ __align__(16) float S[8144];
    float* b1sr = S;                              // 2112 (dead after inv-y)
    float* b1si = S + 2112;                       // 2112
    float* hr   = S;                              // 2056 alias
    float* hi   = S + 2112;                       // 2056 alias
    unsigned short* xsu = (unsigned short*)(S + 4224);   // 32*66 u16 (pitch 66: MFMA-B conflict-free)
    float2* ms  = (float2*)(S + 5280);            // 256 f2
    float* ys   = S + 5792;                       // 2176 pitch 68
    float2* twy = (float2*)(S + 7968);            // 8 f2
    float* cosT = S + 7984;                       // 64
    float* sinT = S + 8048;                       // 64
    float* bias = S + 8112;                       // 32
    int t = threadIdx.x;
    int b, nx, ny; swz8k(blockIdx.x, b, nx, ny);
    int nxy = nx * 64 + ny;

    if (t < 64) { float s, c; sincosf((float)t * (PI_F / 32.0f), &s, &c); cosT[t] = c; sinT[t] = s; }
    if (t >= 64 && t < 72) {
        int ky = t - 64;
        float s, c; sincosf((float)((ky * ny) & 63) * (PI_F / 32.0f), &s, &c);
        twy[ky] = make_float2(c, s);
    }
    if (t >= 96 && t < 128) bias[t - 96] = bb[t - 96];
    {   // stage x (bf16): one uint4 (8 elems) per thread -> xsu pitch 66
        int ch = t >> 3, q = t & 7;
        uint4 v = *(const uint4*)(xin + (((size_t)b) << 23) + (nxy << 6)
                                  + ((size_t)ch << 18) + q * 8);
        unsigned int* dst = (unsigned int*)(xsu + ch * 66 + q * 8);
        dst[0] = v.x; dst[1] = v.y; dst[2] = v.z; dst[3] = v.w;
    }
    const float2* bsrc = b1 + ((size_t)(b * 64 + nx)) * 2048;   // contiguous 16 KB
    for (int u = 0; u < 8; u++) {
        int g = u * 256 + t;
        float2 v = bsrc[g];
        int ky = g & 7, okz = g >> 3;
        b1sr[ky * 264 + okz] = v.x;
        b1si[ky * 264 + okz] = v.y;
    }
    __syncthreads();
    {   // inverse-y with block-uniform twiddles (thread t = o*8+kz)
        float mr = 0.0f, mi = 0.0f;
        #pragma unroll
        for (int ky = 0; ky < 8; ky++) {
            float vr = b1sr[ky * 264 + t], vi = b1si[ky * 264 + t];
            float2 w = twy[ky];
            mr += vr * w.x - vi * w.y;
            mi += vr * w.y + vi * w.x;
        }
        ms[t] = make_float2(mr, mi);
    }
    __syncthreads();

    // ---- MFMA bypass: D[32 o][64 nz] = W[32x32] x X[32x64], 2 tiles/wave ----
    int lane = t & 63;
    int w = rfl(t >> 6);
    int otile = w & 1;
    int nzt0 = (w >> 1) * 2;
    int l15 = lane & 15;
    int quad = lane >> 4;

    U8 af;
    *(uint4*)af.u = *(const uint4*)(wbh + ((otile * 16 + l15) << 5) + (quad << 3));

    const float scale = 1.0f / 262144.0f;
    size_t colbase = (((size_t)b) << 23) + (nxy << 6);
    floatx4 dz = {0.0f, 0.0f, 0.0f, 0.0f};

    #pragma unroll
    for (int m = 0; m < 2; m++) {
        int nzc = (nzt0 + m) * 16 + l15;
        U8 bf_;
        #pragma unroll
        for (int j = 0; j < 8; j++) bf_.u[j] = xsu[(quad * 8 + j) * 66 + nzc];
        floatx4 d = __builtin_amdgcn_mfma_f32_16x16x32_bf16(af.v, bf_.v, dz, 0, 0, 0);

        // per-nzc inverse-z twiddles
        float c7[8], s7[8];
        c7[0] = 1.f; s7[0] = 0.f;
        {
            float cs = cosT[nzc], ss = sinT[nzc];
            #pragma unroll
            for (int kz = 1; kz < 8; kz++) {
                c7[kz] = c7[kz - 1] * cs - s7[kz - 1] * ss;
                s7[kz] = s7[kz - 1] * cs + c7[kz - 1] * ss;
            }
        }
        #pragma unroll
        for (int r = 0; r < 4; r++) {
            int o = otile * 16 + quad * 4 + r;
            const float2* mrow = ms + o * 8;
            float sp = mrow[0].x;
            #pragma unroll
            for (int kz = 1; kz < 8; kz++) {
                float2 mm = mrow[kz];
                sp += 2.0f * (mm.x * c7[kz] - mm.y * s7[kz]);
            }
            float gv = gelu_exact(sp * scale + d[r] + bias[o]);
            xout[colbase + ((size_t)o << 18) + nzc] = f2bf(gv);
            ys[o * 68 + nzc] = gv;
        }
    }

    if (do_z) {
        __syncthreads();             // b1s region dead -> hr/hi may overwrite
        {
            int o = t >> 3, q = t & 7;
            float h[8];
            #pragma unroll
            for (int p = 0; p < 8; p++) h[p] = ys[o * 68 + 8 * p + q];
            rdft8(h, hr, hi, t);
        }
        __syncthreads();
        {
            float2 r = zdft_combine(hr, hi, cosT, sinT, t >> 3, t & 7);
            a1[((size_t)(b * 4096 + nxy)) * 256 + t] = r;
        }
    }
}

// ---------------- projection (bf16 x input) ----------------
__global__ void k_proj(const unsigned short* __restrict__ x4, const float* __restrict__ w1,
                       const float* __restrict__ b1, const float* __restrict__ w2,
                       const float* __restrict__ b2, const float* __restrict__ state_in,
                       float* __restrict__ out) {
    int t = threadIdx.x;
    int g = blockIdx.x * 256 + t;
    int b = rfl(g >> 18);
    int n = g & (262144 - 1);
    float xv[32];
    const unsigned short* xb = x4 + (((size_t)b) << 23) + n;
    #pragma unroll 8
    for (int i = 0; i < 32; i++) xv[i] = bf2f(xb[(size_t)i << 18]);
    float h[32];
    for (int o = 0; o < 32; o++) {
        float a = b1[o];
        const float* w = w1 + o * 32;
        #pragma unroll
        for (int i = 0; i < 32; i++) a += w[i] * xv[i];
        h[o] = gelu_exact(a);
    }
    size_t base = ((size_t)b * 262144 + n) * 4;
    float4 sv = *(const float4*)(state_in + base);
    float r[4];
    for (int j = 0; j < 4; j++) {
        float a = b2[j];
        const float* w = w2 + j * 32;
        #pragma unroll
        for (int o = 0; o < 32; o++) a += w[o] * h[o];
        r[j] = a;
    }
    *(float4*)(out + base) = make_float4(sv.x + 0.05f * r[0], sv.y + 0.05f * r[1],
                                         sv.z + 0.05f * r[2], sv.w + 0.05f * r[3]);
}

extern "C" void kernel_launch(void* const* d_in, const int* in_sizes, int n_in,
                              void* d_out, int out_size, void* d_ws, size_t ws_size,
                              hipStream_t stream) {
    const float* state_in   = (const float*)d_in[0];
    const float* node_pos   = (const float*)d_in[1];
    const float* time_i     = (const float*)d_in[3];
    const float* conditions = (const float*)d_in[4];
    const float* t_embed_w  = (const float*)d_in[5];
    const float* t_embed_b  = (const float*)d_in[6];
    const float* c_embed_w  = (const float*)d_in[7];
    const float* c_embed_b  = (const float*)d_in[8];
    const float* lift_w     = (const float*)d_in[9];
    const float* lift_b     = (const float*)d_in[10];
    const float* spec_wr    = (const float*)d_in[11];
    const float* spec_wi    = (const float*)d_in[12];
    const float* byp_w      = (const float*)d_in[13];
    const float* byp_b      = (const float*)d_in[14];
    const float* proj1_w    = (const float*)d_in[15];
    const float* proj1_b    = (const float*)d_in[16];
    const float* proj2_w    = (const float*)d_in[17];
    const float* proj2_b    = (const float*)d_in[18];
    float* out = (float*)d_out;
    float* ws  = (float*)d_ws;

    unsigned short* xA = (unsigned short*)ws;                    // 16777216 u16
    unsigned short* xB = (unsigned short*)(ws + 8388608);        // 16777216 u16
    float2* a1   = (float2*)(ws + 16777216);    // 2097152 f2 -> ends 20971520
    float2* a2p  = (float2*)(ws + 20971520);    // 524288 f2  -> ends 22020096
    float2* xft  = (float2*)(ws + 22020096);    // 32768 f2   -> ends 22085632
    float2* yftp = (float2*)(ws + 22085632);    // 65536 f2   -> ends 22216704
    float2* b1   = (float2*)(ws + 22216704);    // 262144 f2  -> ends 22740992
    float*  embk = ws + 22740992;               // 64
    unsigned short* wbh = (unsigned short*)(ws + 22741056);   // 4096 u16 -> ends 22743104
    float*  wlT  = ws + 22743104;               // 1184

    k_emb<<<2, 256, 0, stream>>>(time_i, conditions, t_embed_w, t_embed_b,
                                 c_embed_w, c_embed_b, lift_b, embk);
    k_wt<<<21, 256, 0, stream>>>(byp_w, lift_w, wbh, wlT);
    k_lift<<<8192, 256, 0, stream>>>(state_in, node_pos, wlT, embk, xA, a1);

    for (int l = 0; l < 4; l++) {
        unsigned short* xin  = (l & 1) ? xB : xA;
        unsigned short* xout = (l & 1) ? xA : xB;
        const float* wrl = spec_wr + (size_t)l * 524288;
        const float* wil = spec_wi + (size_t)l * 524288;
        k_p1<<<256, 256, 0, stream>>>(a1, a2p);
        k_p2<<<256, 256, 0, stream>>>(a2p, xft);
        k_p3<<<256, 256, 0, stream>>>(xft, wrl, wil, yftp);
        k_p4<<<256, 256, 0, stream>>>(yftp, b1);
        k_fin<<<8192, 256, 0, stream>>>(xin, b1, wbh + l * 1024, byp_b + l * 32,
                                        xout, a1, (l < 3) ? 1 : 0);
    }

    k_proj<<<2048, 256, 0, stream>>>(xA, proj1_w, proj1_b, proj2_w, proj2_b, state_in, out);
}

// Round 10
// 449.653 us; speedup vs baseline: 2.1493x; 1.0552x over previous
//
#include <hip/hip_runtime.h>
#include <math.h>

#define PI_F 3.14159265358979323846f

typedef __bf16 bf16x8 __attribute__((ext_vector_type(8)));
typedef float floatx4 __attribute__((ext_vector_type(4)));
union U8 { unsigned short u[8]; bf16x8 v; };

__device__ __forceinline__ float gelu_exact(float v) {
    return 0.5f * v * (1.0f + erff(v * 0.70710678118654752f));
}
__device__ __forceinline__ int rfl(int x) { return __builtin_amdgcn_readfirstlane(x); }

__device__ __forceinline__ unsigned short f2bf(float f) {   // RNE fp32->bf16
    unsigned int u = __float_as_uint(f);
    u += 0x7fffu + ((u >> 16) & 1u);
    return (unsigned short)(u >> 16);
}
__device__ __forceinline__ float bf2f(unsigned short h) {
    return __uint_as_float(((unsigned int)h) << 16);
}

// XCD-locality swizzle for 8192-block grids (blk%8 -> XCD round-robin).
__device__ __forceinline__ void swz8k(int blk, int& b, int& nx, int& ny) {
    int x = blk & 7;
    int j = blk >> 3;
    int pair = x * 16 + (j >> 6);
    ny = j & 63;
    b = pair >> 6;
    nx = pair & 63;
}

// Radix-8 stage A: 8-pt real DFT; write layout [j][t] pitch 257 -> banks (j+t)%32 (2-way, free)
__device__ __forceinline__ void rdft8(const float h[8], float* __restrict__ hr,
                                      float* __restrict__ hi, int t) {
    const float s2 = 0.70710678118654752f;
    float e0 = h[0] + h[4], e1 = h[1] + h[5], e2 = h[2] + h[6], e3 = h[3] + h[7];
    float o0 = h[0] - h[4], o1 = h[1] - h[5], o2 = h[2] - h[6], o3 = h[3] - h[7];
    float ee = e0 + e2, eo = e1 + e3;
    float H0r = ee + eo, H4r = ee - eo;
    float H2r = e0 - e2, H2i = -(e1 - e3);
    float t13p = s2 * (o1 + o3), t13m = s2 * (o1 - o3);
    float H1r = o0 + t13m, H1i = -o2 - t13p;
    float H3r = o0 - t13m, H3i =  o2 - t13p;
    hr[0 * 257 + t] = H0r;  hi[0 * 257 + t] = 0.0f;
    hr[1 * 257 + t] = H1r;  hi[1 * 257 + t] = H1i;
    hr[2 * 257 + t] = H2r;  hi[2 * 257 + t] = H2i;
    hr[3 * 257 + t] = H3r;  hi[3 * 257 + t] = H3i;
    hr[4 * 257 + t] = H4r;  hi[4 * 257 + t] = 0.0f;
    hr[5 * 257 + t] = H3r;  hi[5 * 257 + t] = -H3i;
    hr[6 * 257 + t] = H2r;  hi[6 * 257 + t] = -H2i;
    hr[7 * 257 + t] = H1r;  hi[7 * 257 + t] = -H1i;
}

// Radix-8 stage B with LDS twiddle tables
__device__ __forceinline__ float2 zdft_combine(const float* __restrict__ hr,
                                               const float* __restrict__ hi,
                                               const float* __restrict__ cosT,
                                               const float* __restrict__ sinT,
                                               int o, int kz) {
    float re = 0.0f, im = 0.0f;
    int base = kz * 257 + o * 8;
    #pragma unroll
    for (int q = 0; q < 8; q++) {
        float Hr = hr[base + q], Hi = hi[base + q];
        int m = (kz * q) & 63;
        float c = cosT[m], s = sinT[m];
        re += Hr * c + Hi * s;          // H * e^{-i kz q pi/32}
        im += Hi * c - Hr * s;
    }
    return make_float2(re, im);
}

// ---------------- emb ----------------
__global__ void k_emb(const float* __restrict__ time_i, const float* __restrict__ conditions,
                      const float* __restrict__ t_embed_w, const float* __restrict__ t_embed_b,
                      const float* __restrict__ c_embed_w, const float* __restrict__ c_embed_b,
                      const float* __restrict__ lift_b, float* __restrict__ embk) {
    __shared__ float red[8][32];
    int t = threadIdx.x;
    int b = blockIdx.x;
    int c = t & 31, lg = t >> 5;
    float acc = 0.0f;
    if (lg == 0) {
        acc = t_embed_b[c] + c_embed_b[c] + lift_b[c];
        float tv = time_i[b];
        float ang = PI_F * tv;
        const float* tw = t_embed_w + c * 11;
        for (int i = 0; i < 5; i++) {
            float s, co; sincosf(ang, &s, &co);
            acc += co * tw[i] + s * tw[5 + i];
            ang *= 2.0f;
        }
        acc += tv * tw[10];
    }
    const float* cw = c_embed_w + c * 352;
    for (int j = 0; j < 4; j++) {
        int l = lg * 4 + j;
        float v = conditions[b * 32 + l];
        float ang = PI_F * v;
        for (int i = 0; i < 5; i++) {
            float s, co; sincosf(ang, &s, &co);
            acc += co * cw[l * 10 + i] + s * cw[l * 10 + 5 + i];
            ang *= 2.0f;
        }
        acc += v * cw[320 + l];
    }
    red[lg][c] = acc;
    __syncthreads();
    if (t < 32) {
        float s = 0.0f;
        for (int g = 0; g < 8; g++) s += red[g][t];
        embk[b * 32 + t] = s;
    }
}

// -------- k_wt: bf16 bypass weights [l][o][i] + transposed lift weights --------
__global__ void k_wt(const float* __restrict__ byp_w, const float* __restrict__ lift_w,
                     unsigned short* __restrict__ wbh, float* __restrict__ wlT) {
    int idx = blockIdx.x * 256 + threadIdx.x;
    if (idx < 4096) {
        wbh[idx] = f2bf(byp_w[idx]);          // same [l][o][i] order (A-fragment layout)
    } else if (idx < 4096 + 1184) {
        int j = idx - 4096;
        int q = j >> 5, o = j & 31;
        wlT[j] = lift_w[o * 37 + q];
    }
}

// ------- k_lift: lift conv + emb, radix-8 forward z-DFT. x0 in bf16. -------
__global__ __launch_bounds__(256) void k_lift(const float* __restrict__ state_in,
        const float* __restrict__ node_pos, const float* __restrict__ wlT,
        const float* __restrict__ embk, unsigned short* __restrict__ x0,
        float2* __restrict__ a1) {
    __shared__ __align__(16) float S[8784];
    float* fs   = S;             // 2368 [q][nz]
    float* ys   = S + 2368;      // 2176 [o][nz] pitch 68
    float* hr   = S + 4544;      // 2056 [j][t] pitch 257
    float* hi   = S + 6600;      // 2056
    float* cosT = S + 8656;      // 64
    float* sinT = S + 8720;      // 64
    int t = threadIdx.x;
    int b, nx, ny; swz8k(blockIdx.x, b, nx, ny);
    int nxy = nx * 64 + ny;

    if (t < 64) { float s, c; sincosf((float)t * (PI_F / 32.0f), &s, &c); cosT[t] = c; sinT[t] = s; }
    if (t < 192) {
        // t = nz*3 + l : coalesced node_pos read, one sincosf + 4 exact doublings
        int nzf = t / 3;
        int l = t - nzf * 3;
        float p = node_pos[((size_t)b * 262144 + (nxy << 6)) * 3 + t];
        float s, c; sincosf(PI_F * p, &s, &c);
        #pragma unroll
        for (int i = 0; i < 5; i++) {
            fs[(4 + l * 10 + i) * 64 + nzf] = c;
            fs[(4 + l * 10 + 5 + i) * 64 + nzf] = s;
            float nc = 2.0f * c * c - 1.0f;
            s = 2.0f * s * c;
            c = nc;
        }
        fs[(34 + l) * 64 + nzf] = p;
    } else {
        int nzf = t - 192;
        const float4 s4 = *(const float4*)(state_in + ((size_t)b * 262144 + (nxy << 6) + nzf) * 4);
        fs[0 * 64 + nzf] = s4.x; fs[1 * 64 + nzf] = s4.y;
        fs[2 * 64 + nzf] = s4.z; fs[3 * 64 + nzf] = s4.w;
    }
    __syncthreads();

    int nz = t & 63;
    int wq = rfl(t >> 6);
    float acc[8];
    #pragma unroll
    for (int k = 0; k < 8; k++) acc[k] = embk[b * 32 + wq * 8 + k];
    #pragma unroll
    for (int q = 0; q < 37; q++) {
        float fq = fs[q * 64 + nz];
        const float* w = wlT + q * 32 + wq * 8;
        #pragma unroll
        for (int k = 0; k < 8; k++) acc[k] += w[k] * fq;
    }
    int n = (nxy << 6) + nz;
    #pragma unroll
    for (int k = 0; k < 8; k++) {
        int o = wq * 8 + k;
        x0[(((size_t)(b * 32 + o)) << 18) + n] = f2bf(acc[k]);
        ys[o * 68 + nz] = acc[k];
    }
    __syncthreads();
    {   // stage A
        int o = t >> 3, q = t & 7;
        float h[8];
        #pragma unroll
        for (int p = 0; p < 8; p++) h[p] = ys[o * 68 + 8 * p + q];
        rdft8(h, hr, hi, t);
    }
    __syncthreads();
    {   // stage B
        float2 r = zdft_combine(hr, hi, cosT, sinT, t >> 3, t & 7);
        a1[((size_t)(b * 4096 + nxy)) * 256 + t] = r;
    }
}

// =================== spectral mid-section: 4 phase kernels ===================

__global__ __launch_bounds__(256) void k_p1(const float2* __restrict__ a1,
                                            float2* __restrict__ a2p) {
    int blk = blockIdx.x, t = threadIdx.x;
    int x = blk & 7, r = blk >> 3;
    int pair = x * 16 + (r & 15);
    int half = r >> 4;
    const float2* src = a1 + ((size_t)(pair * 64 + half * 32)) * 256 + t;
    float accr[8], acci[8];
    #pragma unroll
    for (int k = 0; k < 8; k++) { accr[k] = 0.0f; acci[k] = 0.0f; }
    const float bc = 0.99518472667f;
    const float bs = -0.09801714033f;
    float wc = half ? -1.0f : 1.0f;
    float ws = 0.0f;
    #pragma unroll 4
    for (int j = 0; j < 32; j++) {
        float2 v = src[(size_t)j * 256];
        accr[0] += v.x; acci[0] += v.y;
        float tc = wc, ts = ws;
        #pragma unroll
        for (int ky = 1; ky < 8; ky++) {
            accr[ky] += v.x * tc - v.y * ts;
            acci[ky] += v.x * ts + v.y * tc;
            float nt = tc * wc - ts * ws; ts = ts * wc + tc * ws; tc = nt;
        }
        float nw = wc * bc - ws * bs; ws = ws * bc + wc * bs; wc = nw;
    }
    float4* dst = (float4*)(a2p + (size_t)half * 262144 + ((size_t)(pair * 256 + t)) * 8);
    #pragma unroll
    for (int j = 0; j < 4; j++)
        dst[j] = make_float4(accr[2 * j], acci[2 * j], accr[2 * j + 1], acci[2 * j + 1]);
}

__global__ __launch_bounds__(256) void k_p2(const float2* __restrict__ a2p,
                                            float2* __restrict__ xft) {
    __shared__ __align__(16) float2 SH[1040];
    int blk = blockIdx.x, t = threadIdx.x;
    for (int lu = 0; lu < 2; lu++) {
        int un = blk * 2 + lu;
        int b = un >> 8, ckz = un & 255;
        size_t base = (size_t)b * 131072 + (size_t)ckz * 8;
        for (int e = t; e < 512; e += 256) {
            size_t a = base + (size_t)(e >> 3) * 2048 + (e & 7);
            float2 v0 = a2p[a];
            float2 v1 = a2p[a + 262144];
            SH[lu * 520 + e] = make_float2(v0.x + v1.x, v0.y + v1.y);
        }
    }
    __syncthreads();
    if (t < 128) {
        int lu = t >> 6, out = t & 63;
        int un = blk * 2 + lu;
        int kx = out & 7;
        float sn, cc; sincosf((float)kx * (PI_F / 32.0f), &sn, &cc);
        float bsn = -sn;
        float tc = 1.0f, ts = 0.0f, rr = 0.0f, ri = 0.0f;
        const float2* row = SH + lu * 520 + (out >> 3);
        for (int nx = 0; nx < 64; nx++) {
            float2 v = row[nx * 8];
            rr += v.x * tc - v.y * ts;
            ri += v.x * ts + v.y * tc;
            float nt = tc * cc - ts * bsn; ts = ts * cc + tc * bsn; tc = nt;
        }
        xft[(size_t)un * 64 + out] = make_float2(rr, ri);
    }
}

__global__ __launch_bounds__(256) void k_p3(const float2* __restrict__ xft,
        const float* __restrict__ wr, const float* __restrict__ wi,
        float2* __restrict__ yftp) {
    __shared__ __align__(16) float2 SH[128];
    int blk = blockIdx.x, t = threadIdx.x;
    int unit = blk >> 1, ih = blk & 1;
    int b = unit >> 6, kx = (unit >> 3) & 7, ky = unit & 7;
    if (t < 128) {
        int il = t >> 3, kz = t & 7;
        int i = ih * 16 + il;
        SH[t] = xft[((size_t)((b * 32 + i) * 8 + kz)) * 64 + ky * 8 + kx];
    }
    __syncthreads();
    int o = t >> 3, kz = t & 7;
    float yr = 0.0f, yi = 0.0f;
    for (int il = 0; il < 16; il++) {
        int i = ih * 16 + il;
        float2 xv = SH[il * 8 + kz];
        int wofs = ((i * 32 + o) << 9) + kx * 64 + ky * 8 + kz;
        float wrv = wr[wofs], wiv = wi[wofs];
        yr += xv.x * wrv - xv.y * wiv;
        yi += xv.x * wiv + xv.y * wrv;
    }
    yftp[(size_t)ih * 32768 + ((size_t)((b * 32 + o) * 8 + kz)) * 64 + ky * 8 + kx]
        = make_float2(yr, yi);
}

__global__ __launch_bounds__(256) void k_p4(const float2* __restrict__ yftp,
                                            float2* __restrict__ b1) {
    __shared__ __align__(16) float2 SH[4608];
    int blk = blockIdx.x, t = threadIdx.x;
    for (int u = 0; u < 2; u++) {
        if (u) __syncthreads();
        int unit = blk * 2 + u;
        int b = unit >> 8, nx = (unit >> 2) & 63, og = unit & 3;
        size_t sbase = ((size_t)(b * 32 + og * 8)) * 512;
        for (int e = t; e < 4096; e += 256) {
            float2 v0 = yftp[sbase + e];
            float2 v1 = yftp[32768 + sbase + e];
            SH[(e >> 3) * 9 + (e & 7)] = make_float2(v0.x + v1.x, v0.y + v1.y);
        }
        __syncthreads();
        float cs, ss; sincosf((float)nx * (PI_F / 32.0f), &ss, &cs);
        float2* dst = b1 + ((size_t)(b * 64 + nx)) * 2048 + og * 512;
        for (int h = 0; h < 2; h++) {
            int idx = h * 256 + t;
            const float2* row = SH + idx * 9;
            float c = 1.0f, s = 0.0f, rr = 0.0f, ri = 0.0f;
            #pragma unroll
            for (int kx = 0; kx < 8; kx++) {
                float2 y = row[kx];
                rr += y.x * c - y.y * s;
                ri += y.x * s + y.y * c;
                float nc = c * cs - s * ss; s = s * cs + c * ss; c = nc;
            }
            dst[idx] = make_float2(rr, ri);
        }
    }
}

// ------- k_fin: inverse-y + MFMA bypass (bf16) + inverse-z + gelu
//         + (l<3) radix-8 fwd z-DFT  OR  (l==3) fused projection+residual -------
__global__ __launch_bounds__(256) void k_fin(
        const unsigned short* __restrict__ xin, const float2* __restrict__ b1,
        const unsigned short* __restrict__ wbh, const float* __restrict__ bb,
        unsigned short* __restrict__ xout, float2* __restrict__ a1, int do_z,
        int do_proj, const float* __restrict__ state_in, const float* __restrict__ p1w,
        const float* __restrict__ p1b, const float* __restrict__ p2w,
        const float* __restrict__ p2b, float* __restrict__ outp) {
    __shared__ __align__(16) float S[8144];
    float* b1sr = S;                              // 2112 (dead after inv-y)
    float* b1si = S + 2112;                       // 2112
    float* hr   = S;                              // 2056 alias
    float* hi   = S + 2112;                       // 2056 alias
    float* pr   = S;                              // 1024 alias (proj partials)
    unsigned short* xsu = (unsigned short*)(S + 4224);   // 32*66 u16
    float2* ms  = (float2*)(S + 5280);            // 256 f2
    float* ys   = S + 5792;                       // 2176 pitch 68
    float2* twy = (float2*)(S + 7968);            // 8 f2
    float* cosT = S + 7984;                       // 64
    float* sinT = S + 8048;                       // 64
    float* bias = S + 8112;                       // 32
    int t = threadIdx.x;
    int b, nx, ny; swz8k(blockIdx.x, b, nx, ny);
    int nxy = nx * 64 + ny;

    if (t < 64) { float s, c; sincosf((float)t * (PI_F / 32.0f), &s, &c); cosT[t] = c; sinT[t] = s; }
    if (t >= 64 && t < 72) {
        int ky = t - 64;
        float s, c; sincosf((float)((ky * ny) & 63) * (PI_F / 32.0f), &s, &c);
        twy[ky] = make_float2(c, s);
    }
    if (t >= 96 && t < 128) bias[t - 96] = bb[t - 96];
    {   // stage x (bf16): one uint4 (8 elems) per thread -> xsu pitch 66
        int ch = t >> 3, q = t & 7;
        uint4 v = *(const uint4*)(xin + (((size_t)b) << 23) + (nxy << 6)
                                  + ((size_t)ch << 18) + q * 8);
        unsigned int* dst = (unsigned int*)(xsu + ch * 66 + q * 8);
        dst[0] = v.x; dst[1] = v.y; dst[2] = v.z; dst[3] = v.w;
    }
    const float2* bsrc = b1 + ((size_t)(b * 64 + nx)) * 2048;   // contiguous 16 KB
    for (int u = 0; u < 8; u++) {
        int g = u * 256 + t;
        float2 v = bsrc[g];
        int ky = g & 7, okz = g >> 3;
        b1sr[ky * 264 + okz] = v.x;
        b1si[ky * 264 + okz] = v.y;
    }
    __syncthreads();
    {   // inverse-y with block-uniform twiddles (thread t = o*8+kz)
        float mr = 0.0f, mi = 0.0f;
        #pragma unroll
        for (int ky = 0; ky < 8; ky++) {
            float vr = b1sr[ky * 264 + t], vi = b1si[ky * 264 + t];
            float2 w = twy[ky];
            mr += vr * w.x - vi * w.y;
            mi += vr * w.y + vi * w.x;
        }
        ms[t] = make_float2(mr, mi);
    }
    __syncthreads();

    // ---- MFMA bypass: D[32 o][64 nz] = W[32x32] x X[32x64], 2 tiles/wave ----
    int lane = t & 63;
    int w = rfl(t >> 6);
    int otile = w & 1;
    int nzt0 = (w >> 1) * 2;
    int l15 = lane & 15;
    int quad = lane >> 4;

    U8 af;
    *(uint4*)af.u = *(const uint4*)(wbh + ((otile * 16 + l15) << 5) + (quad << 3));

    const float scale = 1.0f / 262144.0f;
    size_t colbase = (((size_t)b) << 23) + (nxy << 6);
    floatx4 dz = {0.0f, 0.0f, 0.0f, 0.0f};

    #pragma unroll
    for (int m = 0; m < 2; m++) {
        int nzc = (nzt0 + m) * 16 + l15;
        U8 bf_;
        #pragma unroll
        for (int j = 0; j < 8; j++) bf_.u[j] = xsu[(quad * 8 + j) * 66 + nzc];
        floatx4 d = __builtin_amdgcn_mfma_f32_16x16x32_bf16(af.v, bf_.v, dz, 0, 0, 0);

        float c7[8], s7[8];
        c7[0] = 1.f; s7[0] = 0.f;
        {
            float cs = cosT[nzc], ss = sinT[nzc];
            #pragma unroll
            for (int kz = 1; kz < 8; kz++) {
                c7[kz] = c7[kz - 1] * cs - s7[kz - 1] * ss;
                s7[kz] = s7[kz - 1] * cs + c7[kz - 1] * ss;
            }
        }
        #pragma unroll
        for (int r = 0; r < 4; r++) {
            int o = otile * 16 + quad * 4 + r;
            const float2* mrow = ms + o * 8;
            float sp = mrow[0].x;
            #pragma unroll
            for (int kz = 1; kz < 8; kz++) {
                float2 mm = mrow[kz];
                sp += 2.0f * (mm.x * c7[kz] - mm.y * s7[kz]);
            }
            float gv = gelu_exact(sp * scale + d[r] + bias[o]);
            if (!do_proj) xout[colbase + ((size_t)o << 18) + nzc] = f2bf(gv);
            ys[o * 68 + nzc] = gv;
        }
    }

    if (do_z) {
        __syncthreads();             // b1s region dead -> hr/hi may overwrite
        {
            int o = t >> 3, q = t & 7;
            float h[8];
            #pragma unroll
            for (int p = 0; p < 8; p++) h[p] = ys[o * 68 + 8 * p + q];
            rdft8(h, hr, hi, t);
        }
        __syncthreads();
        {
            float2 r = zdft_combine(hr, hi, cosT, sinT, t >> 3, t & 7);
            a1[((size_t)(b * 4096 + nxy)) * 256 + t] = r;
        }
    }

    if (do_proj) {                  // fused proj1 -> gelu -> proj2 -> residual
        __syncthreads();            // b1s/hr region dead -> pr may overwrite
        int nz = t & 63;
        float xv[32];
        #pragma unroll
        for (int i = 0; i < 32; i++) xv[i] = ys[i * 68 + nz];   // 2-way LDS, free
        float r0 = 0.f, r1 = 0.f, r2 = 0.f, r3 = 0.f;
        #pragma unroll
        for (int k = 0; k < 8; k++) {
            int o = w * 8 + k;
            float a = p1b[o];                                   // s_load
            const float* wr = p1w + o * 32;                     // s_load
            #pragma unroll
            for (int i = 0; i < 32; i++) a += wr[i] * xv[i];
            float h = gelu_exact(a);
            r0 += p2w[0 * 32 + o] * h;
            r1 += p2w[1 * 32 + o] * h;
            r2 += p2w[2 * 32 + o] * h;
            r3 += p2w[3 * 32 + o] * h;
        }
        *(float4*)(pr + w * 256 + nz * 4) = make_float4(r0, r1, r2, r3);
        __syncthreads();
        if (t < 64) {
            float4 a0 = *(float4*)(pr + 0 * 256 + t * 4);
            float4 a1_ = *(float4*)(pr + 1 * 256 + t * 4);
            float4 a2 = *(float4*)(pr + 2 * 256 + t * 4);
            float4 a3 = *(float4*)(pr + 3 * 256 + t * 4);
            size_t base = ((size_t)b * 262144 + (nxy << 6) + t) * 4;
            float4 sv = *(const float4*)(state_in + base);
            *(float4*)(outp + base) = make_float4(
                sv.x + 0.05f * (p2b[0] + a0.x + a1_.x + a2.x + a3.x),
                sv.y + 0.05f * (p2b[1] + a0.y + a1_.y + a2.y + a3.y),
                sv.z + 0.05f * (p2b[2] + a0.z + a1_.z + a2.z + a3.z),
                sv.w + 0.05f * (p2b[3] + a0.w + a1_.w + a2.w + a3.w));
        }
    }
}

extern "C" void kernel_launch(void* const* d_in, const int* in_sizes, int n_in,
                              void* d_out, int out_size, void* d_ws, size_t ws_size,
                              hipStream_t stream) {
    const float* state_in   = (const float*)d_in[0];
    const float* node_pos   = (const float*)d_in[1];
    const float* time_i     = (const float*)d_in[3];
    const float* conditions = (const float*)d_in[4];
    const float* t_embed_w  = (const float*)d_in[5];
    const float* t_embed_b  = (const float*)d_in[6];
    const float* c_embed_w  = (const float*)d_in[7];
    const float* c_embed_b  = (const float*)d_in[8];
    const float* lift_w     = (const float*)d_in[9];
    const float* lift_b     = (const float*)d_in[10];
    const float* spec_wr    = (const float*)d_in[11];
    const float* spec_wi    = (const float*)d_in[12];
    const float* byp_w      = (const float*)d_in[13];
    const float* byp_b      = (const float*)d_in[14];
    const float* proj1_w    = (const float*)d_in[15];
    const float* proj1_b    = (const float*)d_in[16];
    const float* proj2_w    = (const float*)d_in[17];
    const float* proj2_b    = (const float*)d_in[18];
    float* out = (float*)d_out;
    float* ws  = (float*)d_ws;

    unsigned short* xA = (unsigned short*)ws;                    // 16777216 u16
    unsigned short* xB = (unsigned short*)(ws + 8388608);        // 16777216 u16
    float2* a1   = (float2*)(ws + 16777216);    // 2097152 f2 -> ends 20971520
    float2* a2p  = (float2*)(ws + 20971520);    // 524288 f2  -> ends 22020096
    float2* xft  = (float2*)(ws + 22020096);    // 32768 f2   -> ends 22085632
    float2* yftp = (float2*)(ws + 22085632);    // 65536 f2   -> ends 22216704
    float2* b1   = (float2*)(ws + 22216704);    // 262144 f2  -> ends 22740992
    float*  embk = ws + 22740992;               // 64
    unsigned short* wbh = (unsigned short*)(ws + 22741056);   // 4096 u16
    float*  wlT  = ws + 22743104;               // 1184

    k_emb<<<2, 256, 0, stream>>>(time_i, conditions, t_embed_w, t_embed_b,
                                 c_embed_w, c_embed_b, lift_b, embk);
    k_wt<<<21, 256, 0, stream>>>(byp_w, lift_w, wbh, wlT);
    k_lift<<<8192, 256, 0, stream>>>(state_in, node_pos, wlT, embk, xA, a1);

    for (int l = 0; l < 4; l++) {
        unsigned short* xin  = (l & 1) ? xB : xA;
        unsigned short* xout = (l & 1) ? xA : xB;
        const float* wrl = spec_wr + (size_t)l * 524288;
        const float* wil = spec_wi + (size_t)l * 524288;
        k_p1<<<256, 256, 0, stream>>>(a1, a2p);
        k_p2<<<256, 256, 0, stream>>>(a2p, xft);
        k_p3<<<256, 256, 0, stream>>>(xft, wrl, wil, yftp);
        k_p4<<<256, 256, 0, stream>>>(yftp, b1);
        k_fin<<<8192, 256, 0, stream>>>(xin, b1, wbh + l * 1024, byp_b + l * 32,
                                        xout, a1, (l < 3) ? 1 : 0, (l == 3) ? 1 : 0,
                                        state_in, proj1_w, proj1_b, proj2_w, proj2_b, out);
    }
}

// Round 11
// 439.045 us; speedup vs baseline: 2.2013x; 1.0242x over previous
//
#include <hip/hip_runtime.h>
#include <math.h>

#define PI_F 3.14159265358979323846f

typedef __bf16 bf16x8 __attribute__((ext_vector_type(8)));
typedef float floatx4 __attribute__((ext_vector_type(4)));
union U8 { unsigned short u[8]; bf16x8 v; };

// tanh-form GELU: ~13 VALU via v_exp_f32 + v_rcp_f32 (err ~3e-3, threshold 0.099)
__device__ __forceinline__ float gelu_fast(float v) {
    float v2 = v * v;
    float u = 0.7978845608028654f * v * fmaf(0.044715f, v2, 1.0f);
    float a = fminf(fmaxf(u * 2.8853900817779268f, -30.0f), 30.0f);  // 2u*log2(e)
    float e = __builtin_amdgcn_exp2f(a);
    float r = __builtin_amdgcn_rcpf(e + 1.0f);
    float th = fmaf(-2.0f, r, 1.0f);            // tanh(u)
    return 0.5f * v * (1.0f + th);
}
__device__ __forceinline__ int rfl(int x) { return __builtin_amdgcn_readfirstlane(x); }

__device__ __forceinline__ unsigned short f2bf(float f) {   // RNE fp32->bf16
    unsigned int u = __float_as_uint(f);
    u += 0x7fffu + ((u >> 16) & 1u);
    return (unsigned short)(u >> 16);
}
__device__ __forceinline__ float bf2f(unsigned short h) {
    return __uint_as_float(((unsigned int)h) << 16);
}

// XCD-locality swizzle for 8192-block grids (blk%8 -> XCD round-robin).
__device__ __forceinline__ void swz8k(int blk, int& b, int& nx, int& ny) {
    int x = blk & 7;
    int j = blk >> 3;
    int pair = x * 16 + (j >> 6);
    ny = j & 63;
    b = pair >> 6;
    nx = pair & 63;
}

// Radix-8 stage A: 8-pt real DFT; write layout [j][t] pitch 257 -> banks (j+t)%32 (2-way, free)
__device__ __forceinline__ void rdft8(const float h[8], float* __restrict__ hr,
                                      float* __restrict__ hi, int t) {
    const float s2 = 0.70710678118654752f;
    float e0 = h[0] + h[4], e1 = h[1] + h[5], e2 = h[2] + h[6], e3 = h[3] + h[7];
    float o0 = h[0] - h[4], o1 = h[1] - h[5], o2 = h[2] - h[6], o3 = h[3] - h[7];
    float ee = e0 + e2, eo = e1 + e3;
    float H0r = ee + eo, H4r = ee - eo;
    float H2r = e0 - e2, H2i = -(e1 - e3);
    float t13p = s2 * (o1 + o3), t13m = s2 * (o1 - o3);
    float H1r = o0 + t13m, H1i = -o2 - t13p;
    float H3r = o0 - t13m, H3i =  o2 - t13p;
    hr[0 * 257 + t] = H0r;  hi[0 * 257 + t] = 0.0f;
    hr[1 * 257 + t] = H1r;  hi[1 * 257 + t] = H1i;
    hr[2 * 257 + t] = H2r;  hi[2 * 257 + t] = H2i;
    hr[3 * 257 + t] = H3r;  hi[3 * 257 + t] = H3i;
    hr[4 * 257 + t] = H4r;  hi[4 * 257 + t] = 0.0f;
    hr[5 * 257 + t] = H3r;  hi[5 * 257 + t] = -H3i;
    hr[6 * 257 + t] = H2r;  hi[6 * 257 + t] = -H2i;
    hr[7 * 257 + t] = H1r;  hi[7 * 257 + t] = -H1i;
}

// Radix-8 stage B with LDS twiddle tables
__device__ __forceinline__ float2 zdft_combine(const float* __restrict__ hr,
                                               const float* __restrict__ hi,
                                               const float* __restrict__ cosT,
                                               const float* __restrict__ sinT,
                                               int o, int kz) {
    float re = 0.0f, im = 0.0f;
    int base = kz * 257 + o * 8;
    #pragma unroll
    for (int q = 0; q < 8; q++) {
        float Hr = hr[base + q], Hi = hi[base + q];
        int m = (kz * q) & 63;
        float c = cosT[m], s = sinT[m];
        re += Hr * c + Hi * s;          // H * e^{-i kz q pi/32}
        im += Hi * c - Hr * s;
    }
    return make_float2(re, im);
}

// ---------------- emb ----------------
__global__ void k_emb(const float* __restrict__ time_i, const float* __restrict__ conditions,
                      const float* __restrict__ t_embed_w, const float* __restrict__ t_embed_b,
                      const float* __restrict__ c_embed_w, const float* __restrict__ c_embed_b,
                      const float* __restrict__ lift_b, float* __restrict__ embk) {
    __shared__ float red[8][32];
    int t = threadIdx.x;
    int b = blockIdx.x;
    int c = t & 31, lg = t >> 5;
    float acc = 0.0f;
    if (lg == 0) {
        acc = t_embed_b[c] + c_embed_b[c] + lift_b[c];
        float tv = time_i[b];
        float ang = PI_F * tv;
        const float* tw = t_embed_w + c * 11;
        for (int i = 0; i < 5; i++) {
            float s, co; sincosf(ang, &s, &co);
            acc += co * tw[i] + s * tw[5 + i];
            ang *= 2.0f;
        }
        acc += tv * tw[10];
    }
    const float* cw = c_embed_w + c * 352;
    for (int j = 0; j < 4; j++) {
        int l = lg * 4 + j;
        float v = conditions[b * 32 + l];
        float ang = PI_F * v;
        for (int i = 0; i < 5; i++) {
            float s, co; sincosf(ang, &s, &co);
            acc += co * cw[l * 10 + i] + s * cw[l * 10 + 5 + i];
            ang *= 2.0f;
        }
        acc += v * cw[320 + l];
    }
    red[lg][c] = acc;
    __syncthreads();
    if (t < 32) {
        float s = 0.0f;
        for (int g = 0; g < 8; g++) s += red[g][t];
        embk[b * 32 + t] = s;
    }
}

// -------- k_wt: bf16 bypass weights [l][o][i] + transposed lift weights --------
__global__ void k_wt(const float* __restrict__ byp_w, const float* __restrict__ lift_w,
                     unsigned short* __restrict__ wbh, float* __restrict__ wlT) {
    int idx = blockIdx.x * 256 + threadIdx.x;
    if (idx < 4096) {
        wbh[idx] = f2bf(byp_w[idx]);          // same [l][o][i] order (A-fragment layout)
    } else if (idx < 4096 + 1184) {
        int j = idx - 4096;
        int q = j >> 5, o = j & 31;
        wlT[j] = lift_w[o * 37 + q];
    }
}

// ------- k_lift: lift conv + emb, radix-8 forward z-DFT. x0 in bf16. -------
__global__ __launch_bounds__(256) void k_lift(const float* __restrict__ state_in,
        const float* __restrict__ node_pos, const float* __restrict__ wlT,
        const float* __restrict__ embk, unsigned short* __restrict__ x0,
        float2* __restrict__ a1) {
    __shared__ __align__(16) float S[8784];
    float* fs   = S;             // 2368 [q][nz]
    float* ys   = S + 2368;      // 2176 [o][nz] pitch 68
    float* hr   = S + 4544;      // 2056 [j][t] pitch 257
    float* hi   = S + 6600;      // 2056
    float* cosT = S + 8656;      // 64
    float* sinT = S + 8720;      // 64
    int t = threadIdx.x;
    int b, nx, ny; swz8k(blockIdx.x, b, nx, ny);
    int nxy = nx * 64 + ny;

    if (t < 64) { float s, c; sincosf((float)t * (PI_F / 32.0f), &s, &c); cosT[t] = c; sinT[t] = s; }
    if (t < 192) {
        // t = nz*3 + l : coalesced node_pos read, one sincosf + 4 exact doublings
        int nzf = t / 3;
        int l = t - nzf * 3;
        float p = node_pos[((size_t)b * 262144 + (nxy << 6)) * 3 + t];
        float s, c; sincosf(PI_F * p, &s, &c);
        #pragma unroll
        for (int i = 0; i < 5; i++) {
            fs[(4 + l * 10 + i) * 64 + nzf] = c;
            fs[(4 + l * 10 + 5 + i) * 64 + nzf] = s;
            float nc = 2.0f * c * c - 1.0f;
            s = 2.0f * s * c;
            c = nc;
        }
        fs[(34 + l) * 64 + nzf] = p;
    } else {
        int nzf = t - 192;
        const float4 s4 = *(const float4*)(state_in + ((size_t)b * 262144 + (nxy << 6) + nzf) * 4);
        fs[0 * 64 + nzf] = s4.x; fs[1 * 64 + nzf] = s4.y;
        fs[2 * 64 + nzf] = s4.z; fs[3 * 64 + nzf] = s4.w;
    }
    __syncthreads();

    int nz = t & 63;
    int wq = rfl(t >> 6);
    float acc[8];
    #pragma unroll
    for (int k = 0; k < 8; k++) acc[k] = embk[b * 32 + wq * 8 + k];
    #pragma unroll
    for (int q = 0; q < 37; q++) {
        float fq = fs[q * 64 + nz];
        const float* w = wlT + q * 32 + wq * 8;
        #pragma unroll
        for (int k = 0; k < 8; k++) acc[k] += w[k] * fq;
    }
    int n = (nxy << 6) + nz;
    #pragma unroll
    for (int k = 0; k < 8; k++) {
        int o = wq * 8 + k;
        x0[(((size_t)(b * 32 + o)) << 18) + n] = f2bf(acc[k]);
        ys[o * 68 + nz] = acc[k];
    }
    __syncthreads();
    {   // stage A
        int o = t >> 3, q = t & 7;
        float h[8];
        #pragma unroll
        for (int p = 0; p < 8; p++) h[p] = ys[o * 68 + 8 * p + q];
        rdft8(h, hr, hi, t);
    }
    __syncthreads();
    {   // stage B
        float2 r = zdft_combine(hr, hi, cosT, sinT, t >> 3, t & 7);
        a1[((size_t)(b * 4096 + nxy)) * 256 + t] = r;
    }
}

// =================== spectral mid-section: 4 phase kernels ===================

__global__ __launch_bounds__(256) void k_p1(const float2* __restrict__ a1,
                                            float2* __restrict__ a2p) {
    int blk = blockIdx.x, t = threadIdx.x;
    int x = blk & 7, r = blk >> 3;
    int pair = x * 16 + (r & 15);
    int half = r >> 4;
    const float2* src = a1 + ((size_t)(pair * 64 + half * 32)) * 256 + t;
    float accr[8], acci[8];
    #pragma unroll
    for (int k = 0; k < 8; k++) { accr[k] = 0.0f; acci[k] = 0.0f; }
    const float bc = 0.99518472667f;
    const float bs = -0.09801714033f;
    float wc = half ? -1.0f : 1.0f;
    float ws = 0.0f;
    #pragma unroll 4
    for (int j = 0; j < 32; j++) {
        float2 v = src[(size_t)j * 256];
        accr[0] += v.x; acci[0] += v.y;
        float tc = wc, ts = ws;
        #pragma unroll
        for (int ky = 1; ky < 8; ky++) {
            accr[ky] += v.x * tc - v.y * ts;
            acci[ky] += v.x * ts + v.y * tc;
            float nt = tc * wc - ts * ws; ts = ts * wc + tc * ws; tc = nt;
        }
        float nw = wc * bc - ws * bs; ws = ws * bc + wc * bs; wc = nw;
    }
    float4* dst = (float4*)(a2p + (size_t)half * 262144 + ((size_t)(pair * 256 + t)) * 8);
    #pragma unroll
    for (int j = 0; j < 4; j++)
        dst[j] = make_float4(accr[2 * j], acci[2 * j], accr[2 * j + 1], acci[2 * j + 1]);
}

__global__ __launch_bounds__(256) void k_p2(const float2* __restrict__ a2p,
                                            float2* __restrict__ xft) {
    __shared__ __align__(16) float2 SH[1040];
    int blk = blockIdx.x, t = threadIdx.x;
    for (int lu = 0; lu < 2; lu++) {
        int un = blk * 2 + lu;
        int b = un >> 8, ckz = un & 255;
        size_t base = (size_t)b * 131072 + (size_t)ckz * 8;
        for (int e = t; e < 512; e += 256) {
            size_t a = base + (size_t)(e >> 3) * 2048 + (e & 7);
            float2 v0 = a2p[a];
            float2 v1 = a2p[a + 262144];
            SH[lu * 520 + e] = make_float2(v0.x + v1.x, v0.y + v1.y);
        }
    }
    __syncthreads();
    if (t < 128) {
        int lu = t >> 6, out = t & 63;
        int un = blk * 2 + lu;
        int kx = out & 7;
        float sn, cc; sincosf((float)kx * (PI_F / 32.0f), &sn, &cc);
        float bsn = -sn;
        float tc = 1.0f, ts = 0.0f, rr = 0.0f, ri = 0.0f;
        const float2* row = SH + lu * 520 + (out >> 3);
        for (int nx = 0; nx < 64; nx++) {
            float2 v = row[nx * 8];
            rr += v.x * tc - v.y * ts;
            ri += v.x * ts + v.y * tc;
            float nt = tc * cc - ts * bsn; ts = ts * cc + tc * bsn; tc = nt;
        }
        xft[(size_t)un * 64 + out] = make_float2(rr, ri);
    }
}

__global__ __launch_bounds__(256) void k_p3(const float2* __restrict__ xft,
        const float* __restrict__ wr, const float* __restrict__ wi,
        float2* __restrict__ yftp) {
    __shared__ __align__(16) float2 SH[128];
    int blk = blockIdx.x, t = threadIdx.x;
    int unit = blk >> 1, ih = blk & 1;
    int b = unit >> 6, kx = (unit >> 3) & 7, ky = unit & 7;
    if (t < 128) {
        int il = t >> 3, kz = t & 7;
        int i = ih * 16 + il;
        SH[t] = xft[((size_t)((b * 32 + i) * 8 + kz)) * 64 + ky * 8 + kx];
    }
    __syncthreads();
    int o = t >> 3, kz = t & 7;
    float yr = 0.0f, yi = 0.0f;
    for (int il = 0; il < 16; il++) {
        int i = ih * 16 + il;
        float2 xv = SH[il * 8 + kz];
        int wofs = ((i * 32 + o) << 9) + kx * 64 + ky * 8 + kz;
        float wrv = wr[wofs], wiv = wi[wofs];
        yr += xv.x * wrv - xv.y * wiv;
        yi += xv.x * wiv + xv.y * wrv;
    }
    yftp[(size_t)ih * 32768 + ((size_t)((b * 32 + o) * 8 + kz)) * 64 + ky * 8 + kx]
        = make_float2(yr, yi);
}

__global__ __launch_bounds__(256) void k_p4(const float2* __restrict__ yftp,
                                            float2* __restrict__ b1) {
    __shared__ __align__(16) float2 SH[4608];
    int blk = blockIdx.x, t = threadIdx.x;
    for (int u = 0; u < 2; u++) {
        if (u) __syncthreads();
        int unit = blk * 2 + u;
        int b = unit >> 8, nx = (unit >> 2) & 63, og = unit & 3;
        size_t sbase = ((size_t)(b * 32 + og * 8)) * 512;
        for (int e = t; e < 4096; e += 256) {
            float2 v0 = yftp[sbase + e];
            float2 v1 = yftp[32768 + sbase + e];
            SH[(e >> 3) * 9 + (e & 7)] = make_float2(v0.x + v1.x, v0.y + v1.y);
        }
        __syncthreads();
        float cs, ss; sincosf((float)nx * (PI_F / 32.0f), &ss, &cs);
        float2* dst = b1 + ((size_t)(b * 64 + nx)) * 2048 + og * 512;
        for (int h = 0; h < 2; h++) {
            int idx = h * 256 + t;
            const float2* row = SH + idx * 9;
            float c = 1.0f, s = 0.0f, rr = 0.0f, ri = 0.0f;
            #pragma unroll
            for (int kx = 0; kx < 8; kx++) {
                float2 y = row[kx];
                rr += y.x * c - y.y * s;
                ri += y.x * s + y.y * c;
                float nc = c * cs - s * ss; s = s * cs + c * ss; c = nc;
            }
            dst[idx] = make_float2(rr, ri);
        }
    }
}

// ------- k_fin: inverse-y + MFMA bypass (bf16) + inverse-z + gelu
//         + (l<3) radix-8 fwd z-DFT  OR  (l==3) fused projection+residual -------
__global__ __launch_bounds__(256) void k_fin(
        const unsigned short* __restrict__ xin, const float2* __restrict__ b1,
        const unsigned short* __restrict__ wbh, const float* __restrict__ bb,
        unsigned short* __restrict__ xout, float2* __restrict__ a1, int do_z,
        int do_proj, const float* __restrict__ state_in, const float* __restrict__ p1w,
        const float* __restrict__ p1b, const float* __restrict__ p2w,
        const float* __restrict__ p2b, float* __restrict__ outp) {
    __shared__ __align__(16) float S[8240];
    float* b1sr = S;                              // 2112 (dead after inv-y)
    float* b1si = S + 2112;                       // 2112
    float* hr   = S;                              // 2056 alias
    float* hi   = S + 2112;                       // 2056 alias
    float* pr   = S;                              // 1024 alias (proj partials)
    unsigned short* xsu = (unsigned short*)(S + 4224);   // 32*66 u16 = 1056 f
    float2* ms  = (float2*)(S + 5280);            // 288 f2 (pitch 9: quad-conflict-free)
    float* ys   = S + 5856;                       // 2176 pitch 68
    float* cosT = S + 8032;                       // 64
    float* sinT = S + 8096;                       // 64
    float* bias = S + 8160;                       // 32
    int t = threadIdx.x;
    int b, nx, ny; swz8k(blockIdx.x, b, nx, ny);
    int nxy = nx * 64 + ny;

    if (t < 64) { float s, c; sincosf((float)t * (PI_F / 32.0f), &s, &c); cosT[t] = c; sinT[t] = s; }
    if (t >= 96 && t < 128) bias[t - 96] = bb[t - 96];
    {   // stage x (bf16): one uint4 (8 elems) per thread -> xsu pitch 66
        int ch = t >> 3, q = t & 7;
        uint4 v = *(const uint4*)(xin + (((size_t)b) << 23) + (nxy << 6)
                                  + ((size_t)ch << 18) + q * 8);
        unsigned int* dst = (unsigned int*)(xsu + ch * 66 + q * 8);
        dst[0] = v.x; dst[1] = v.y; dst[2] = v.z; dst[3] = v.w;
    }
    const float2* bsrc = b1 + ((size_t)(b * 64 + nx)) * 2048;   // contiguous 16 KB
    for (int u = 0; u < 8; u++) {
        int g = u * 256 + t;
        float2 v = bsrc[g];
        int ky = g & 7, okz = g >> 3;
        b1sr[ky * 264 + okz] = v.x;
        b1si[ky * 264 + okz] = v.y;
    }
    __syncthreads();
    const float scale = 1.0f / 262144.0f;
    {   // inverse-y, twiddles from LDS tables (block-uniform -> broadcast reads);
        // scale factors folded into ms
        float mr = 0.0f, mi = 0.0f;
        #pragma unroll
        for (int ky = 0; ky < 8; ky++) {
            float vr = b1sr[ky * 264 + t], vi = b1si[ky * 264 + t];
            int m_ = (ky * ny) & 63;
            float c = cosT[m_], s = sinT[m_];
            mr += vr * c - vi * s;        // e^{+i ky ny θ}
            mi += vr * s + vi * c;
        }
        int kz = t & 7;
        float sc = (kz == 0) ? scale : 2.0f * scale;
        ms[(t >> 3) * 9 + kz] = make_float2(mr * sc, mi * sc);
    }
    __syncthreads();

    // ---- MFMA bypass: D[32 o][64 nz] = W[32x32] x X[32x64], 2 tiles/wave ----
    int lane = t & 63;
    int w = rfl(t >> 6);
    int otile = w & 1;
    int nzt0 = (w >> 1) * 2;
    int l15 = lane & 15;
    int quad = lane >> 4;

    U8 af;
    *(uint4*)af.u = *(const uint4*)(wbh + ((otile * 16 + l15) << 5) + (quad << 3));

    size_t colbase = (((size_t)b) << 23) + (nxy << 6);
    floatx4 dz = {0.0f, 0.0f, 0.0f, 0.0f};

    #pragma unroll
    for (int m = 0; m < 2; m++) {
        int nzc = (nzt0 + m) * 16 + l15;
        U8 bf_;
        #pragma unroll
        for (int j = 0; j < 8; j++) bf_.u[j] = xsu[(quad * 8 + j) * 66 + nzc];
        floatx4 d = __builtin_amdgcn_mfma_f32_16x16x32_bf16(af.v, bf_.v, dz, 0, 0, 0);

        // inverse-z twiddles from LDS tables (kz=0 -> 1,0)
        float c7[8], s7[8];
        c7[0] = 1.f; s7[0] = 0.f;
        #pragma unroll
        for (int kz = 1; kz < 8; kz++) {
            int m_ = (kz * nzc) & 63;
            c7[kz] = cosT[m_];
            s7[kz] = sinT[m_];
        }
        #pragma unroll
        for (int r = 0; r < 4; r++) {
            int o = otile * 16 + quad * 4 + r;
            const float2* mrow = ms + o * 9;       // banks spread across quads (pitch 9)
            float sp = 0.0f;
            #pragma unroll
            for (int kz = 0; kz < 8; kz++) {
                float2 mm = mrow[kz];
                sp += mm.x * c7[kz] - mm.y * s7[kz];
            }
            float gv = gelu_fast(sp + d[r] + bias[o]);
            if (!do_proj) xout[colbase + ((size_t)o << 18) + nzc] = f2bf(gv);
            ys[o * 68 + nzc] = gv;
        }
    }

    if (do_z) {
        __syncthreads();             // b1s region dead -> hr/hi may overwrite
        {
            int o = t >> 3, q = t & 7;
            float h[8];
            #pragma unroll
            for (int p = 0; p < 8; p++) h[p] = ys[o * 68 + 8 * p + q];
            rdft8(h, hr, hi, t);
        }
        __syncthreads();
        {
            float2 r = zdft_combine(hr, hi, cosT, sinT, t >> 3, t & 7);
            a1[((size_t)(b * 4096 + nxy)) * 256 + t] = r;
        }
    }

    if (do_proj) {                  // fused proj1 -> gelu -> proj2 -> residual
        __syncthreads();            // b1s/hr region dead -> pr may overwrite
        int nz = t & 63;
        float xv[32];
        #pragma unroll
        for (int i = 0; i < 32; i++) xv[i] = ys[i * 68 + nz];   // 2-way LDS, free
        float r0 = 0.f, r1 = 0.f, r2 = 0.f, r3 = 0.f;
        #pragma unroll
        for (int k = 0; k < 8; k++) {
            int o = w * 8 + k;
            float a = p1b[o];                                   // s_load
            const float* wr = p1w + o * 32;                     // s_load
            #pragma unroll
            for (int i = 0; i < 32; i++) a += wr[i] * xv[i];
            float h = gelu_fast(a);
            r0 += p2w[0 * 32 + o] * h;
            r1 += p2w[1 * 32 + o] * h;
            r2 += p2w[2 * 32 + o] * h;
            r3 += p2w[3 * 32 + o] * h;
        }
        *(float4*)(pr + w * 256 + nz * 4) = make_float4(r0, r1, r2, r3);
        __syncthreads();
        if (t < 64) {
            float4 a0 = *(float4*)(pr + 0 * 256 + t * 4);
            float4 a1_ = *(float4*)(pr + 1 * 256 + t * 4);
            float4 a2 = *(float4*)(pr + 2 * 256 + t * 4);
            float4 a3 = *(float4*)(pr + 3 * 256 + t * 4);
            size_t base = ((size_t)b * 262144 + (nxy << 6) + t) * 4;
            float4 sv = *(const float4*)(state_in + base);
            *(float4*)(outp + base) = make_float4(
                sv.x + 0.05f * (p2b[0] + a0.x + a1_.x + a2.x + a3.x),
                sv.y + 0.05f * (p2b[1] + a0.y + a1_.y + a2.y + a3.y),
                sv.z + 0.05f * (p2b[2] + a0.z + a1_.z + a2.z + a3.z),
                sv.w + 0.05f * (p2b[3] + a0.w + a1_.w + a2.w + a3.w));
        }
    }
}

extern "C" void kernel_launch(void* const* d_in, const int* in_sizes, int n_in,
                              void* d_out, int out_size, void* d_ws, size_t ws_size,
                              hipStream_t stream) {
    const float* state_in   = (const float*)d_in[0];
    const float* node_pos   = (const float*)d_in[1];
    const float* time_i     = (const float*)d_in[3];
    const float* conditions = (const float*)d_in[4];
    const float* t_embed_w  = (const float*)d_in[5];
    const float* t_embed_b  = (const float*)d_in[6];
    const float* c_embed_w  = (const float*)d_in[7];
    const float* c_embed_b  = (const float*)d_in[8];
    const float* lift_w     = (const float*)d_in[9];
    const float* lift_b     = (const float*)d_in[10];
    const float* spec_wr    = (const float*)d_in[11];
    const float* spec_wi    = (const float*)d_in[12];
    const float* byp_w      = (const float*)d_in[13];
    const float* byp_b      = (const float*)d_in[14];
    const float* proj1_w    = (const float*)d_in[15];
    const float* proj1_b    = (const float*)d_in[16];
    const float* proj2_w    = (const float*)d_in[17];
    const float* proj2_b    = (const float*)d_in[18];
    float* out = (float*)d_out;
    float* ws  = (float*)d_ws;

    unsigned short* xA = (unsigned short*)ws;                    // 16777216 u16
    unsigned short* xB = (unsigned short*)(ws + 8388608);        // 16777216 u16
    float2* a1   = (float2*)(ws + 16777216);    // 2097152 f2 -> ends 20971520
    float2* a2p  = (float2*)(ws + 20971520);    // 524288 f2  -> ends 22020096
    float2* xft  = (float2*)(ws + 22020096);    // 32768 f2   -> ends 22085632
    float2* yftp = (float2*)(ws + 22085632);    // 65536 f2   -> ends 22216704
    float2* b1   = (float2*)(ws + 22216704);    // 262144 f2  -> ends 22740992
    float*  embk = ws + 22740992;               // 64
    unsigned short* wbh = (unsigned short*)(ws + 22741056);   // 4096 u16
    float*  wlT  = ws + 22743104;               // 1184

    k_emb<<<2, 256, 0, stream>>>(time_i, conditions, t_embed_w, t_embed_b,
                                 c_embed_w, c_embed_b, lift_b, embk);
    k_wt<<<21, 256, 0, stream>>>(byp_w, lift_w, wbh, wlT);
    k_lift<<<8192, 256, 0, stream>>>(state_in, node_pos, wlT, embk, xA, a1);

    for (int l = 0; l < 4; l++) {
        unsigned short* xin  = (l & 1) ? xB : xA;
        unsigned short* xout = (l & 1) ? xA : xB;
        const float* wrl = spec_wr + (size_t)l * 524288;
        const float* wil = spec_wi + (size_t)l * 524288;
        k_p1<<<256, 256, 0, stream>>>(a1, a2p);
        k_p2<<<256, 256, 0, stream>>>(a2p, xft);
        k_p3<<<256, 256, 0, stream>>>(xft, wrl, wil, yftp);
        k_p4<<<256, 256, 0, stream>>>(yftp, b1);
        k_fin<<<8192, 256, 0, stream>>>(xin, b1, wbh + l * 1024, byp_b + l * 32,
                                        xout, a1, (l < 3) ? 1 : 0, (l == 3) ? 1 : 0,
                                        state_in, proj1_w, proj1_b, proj2_w, proj2_b, out);
    }
}

// Round 12
// 375.746 us; speedup vs baseline: 2.5721x; 1.1685x over previous
//
#include <hip/hip_runtime.h>
#include <math.h>

#define PI_F 3.14159265358979323846f

typedef __bf16 bf16x8 __attribute__((ext_vector_type(8)));
typedef float floatx4 __attribute__((ext_vector_type(4)));
union U8 { unsigned short u[8]; uint4 q; bf16x8 v; };

// tanh-form GELU: ~13 VALU via v_exp_f32 + v_rcp_f32
__device__ __forceinline__ float gelu_fast(float v) {
    float v2 = v * v;
    float u = 0.7978845608028654f * v * fmaf(0.044715f, v2, 1.0f);
    float a = fminf(fmaxf(u * 2.8853900817779268f, -30.0f), 30.0f);
    float e = __builtin_amdgcn_exp2f(a);
    float r = __builtin_amdgcn_rcpf(e + 1.0f);
    float th = fmaf(-2.0f, r, 1.0f);
    return 0.5f * v * (1.0f + th);
}
__device__ __forceinline__ int rfl(int x) { return __builtin_amdgcn_readfirstlane(x); }

__device__ __forceinline__ unsigned short f2bf(float f) {   // RNE fp32->bf16
    unsigned int u = __float_as_uint(f);
    u += 0x7fffu + ((u >> 16) & 1u);
    return (unsigned short)(u >> 16);
}
__device__ __forceinline__ float bf2f(unsigned short h) {
    return __uint_as_float(((unsigned int)h) << 16);
}

// XCD-locality swizzle for 8192-block grids (blk%8 -> XCD round-robin).
__device__ __forceinline__ void swz8k(int blk, int& b, int& nx, int& ny) {
    int x = blk & 7;
    int j = blk >> 3;
    int pair = x * 16 + (j >> 6);
    ny = j & 63;
    b = pair >> 6;
    nx = pair & 63;
}

// ---------------- emb ----------------
__global__ void k_emb(const float* __restrict__ time_i, const float* __restrict__ conditions,
                      const float* __restrict__ t_embed_w, const float* __restrict__ t_embed_b,
                      const float* __restrict__ c_embed_w, const float* __restrict__ c_embed_b,
                      const float* __restrict__ lift_b, float* __restrict__ embk) {
    __shared__ float red[8][32];
    int t = threadIdx.x;
    int b = blockIdx.x;
    int c = t & 31, lg = t >> 5;
    float acc = 0.0f;
    if (lg == 0) {
        acc = t_embed_b[c] + c_embed_b[c] + lift_b[c];
        float tv = time_i[b];
        float ang = PI_F * tv;
        const float* tw = t_embed_w + c * 11;
        for (int i = 0; i < 5; i++) {
            float s, co; sincosf(ang, &s, &co);
            acc += co * tw[i] + s * tw[5 + i];
            ang *= 2.0f;
        }
        acc += tv * tw[10];
    }
    const float* cw = c_embed_w + c * 352;
    for (int j = 0; j < 4; j++) {
        int l = lg * 4 + j;
        float v = conditions[b * 32 + l];
        float ang = PI_F * v;
        for (int i = 0; i < 5; i++) {
            float s, co; sincosf(ang, &s, &co);
            acc += co * cw[l * 10 + i] + s * cw[l * 10 + 5 + i];
            ang *= 2.0f;
        }
        acc += v * cw[320 + l];
    }
    red[lg][c] = acc;
    __syncthreads();
    if (t < 32) {
        float s = 0.0f;
        for (int g = 0; g < 8; g++) s += red[g][t];
        embk[b * 32 + t] = s;
    }
}

// -------- k_wt: bf16 constants: bypass W, lift W (K-padded), inv-z / fwd-z twiddles -----
__global__ void k_wt(const float* __restrict__ byp_w, const float* __restrict__ lift_w,
                     unsigned short* __restrict__ wbh, unsigned short* __restrict__ wlbf,
                     unsigned short* __restrict__ Tinv, unsigned short* __restrict__ TfT) {
    int idx = blockIdx.x * 256 + threadIdx.x;
    const float th = PI_F / 32.0f;
    if (idx < 4096) {
        wbh[idx] = f2bf(byp_w[idx]);          // [l][o][i] (A-fragment layout)
    } else if (idx < 6144) {
        int j = idx - 4096;                   // o*64 + q
        int o = j >> 6, q = j & 63;
        wlbf[j] = (q < 37) ? f2bf(lift_w[o * 37 + q]) : 0;
    } else if (idx < 8192) {
        int j = idx - 6144;                   // nz*32 + k
        int nz = j >> 5, k = j & 31;
        int kz = k >> 1;
        float val = 0.0f;
        if (kz < 8) {
            float a = (float)((kz * nz) & 63) * th;
            val = (k & 1) ? sinf(a) : cosf(a);
        }
        Tinv[j] = f2bf(val);
    } else if (idx < 9216) {
        int j = idx - 8192;                   // kcol*64 + nz
        int kcol = j >> 6, nz = j & 63;
        int kz = kcol >> 1;
        float a = (float)((kz * nz) & 63) * th;
        float val = (kcol & 1) ? -sinf(a) : cosf(a);
        TfT[j] = f2bf(val);
    }
}

// ------- k_lift: MFMA lift conv + emb + MFMA forward z-DFT. x0 in bf16. -------
__global__ __launch_bounds__(256) void k_lift(const float* __restrict__ state_in,
        const float* __restrict__ node_pos, const unsigned short* __restrict__ wlbf,
        const float* __restrict__ embk, const unsigned short* __restrict__ TfT,
        unsigned short* __restrict__ x0, float2* __restrict__ a1) {
    __shared__ __align__(16) float SL[7584];
    unsigned short* fsT  = (unsigned short*)SL;          // [nz][72] u16 (2304 f)
    unsigned short* ysbf = (unsigned short*)(SL + 2304); // [o][72] u16 (1152 f)
    float* pz   = SL + 3456;                             // 4096 f
    float* bias = SL + 7552;                             // 32
    int t = threadIdx.x;
    int b, nx, ny; swz8k(blockIdx.x, b, nx, ny);
    int nxy = nx * 64 + ny;

    if (t < 32) bias[t] = embk[b * 32 + t];
    {   // zero-pad feature cols 37..68 (u16 writes; no byte overlap with writers)
        for (int u = t; u < 2048; u += 256) {
            int row = u >> 5, col = 37 + (u & 31);
            fsT[row * 72 + col] = 0;
        }
    }
    if (t < 192) {
        // t = nz*3 + l : coalesced node_pos read, one sincosf + 4 exact doublings
        int nzf = t / 3;
        int l = t - nzf * 3;
        float p = node_pos[((size_t)b * 262144 + (nxy << 6)) * 3 + t];
        float s, c; sincosf(PI_F * p, &s, &c);
        unsigned short* row = fsT + nzf * 72;
        #pragma unroll
        for (int i = 0; i < 5; i++) {
            row[4 + l * 10 + i] = f2bf(c);
            row[4 + l * 10 + 5 + i] = f2bf(s);
            float nc = 2.0f * c * c - 1.0f;
            s = 2.0f * s * c;
            c = nc;
        }
        row[34 + l] = f2bf(p);
    } else {
        int nzf = t - 192;
        const float4 s4 = *(const float4*)(state_in + ((size_t)b * 262144 + (nxy << 6) + nzf) * 4);
        unsigned short* row = fsT + nzf * 72;
        row[0] = f2bf(s4.x); row[1] = f2bf(s4.y);
        row[2] = f2bf(s4.z); row[3] = f2bf(s4.w);
    }
    __syncthreads();

    int lane = t & 63;
    int w = rfl(t >> 6);
    int otile = w & 1;
    int nzt0 = (w >> 1) * 2;
    int l15 = lane & 15;
    int quad = lane >> 4;

    U8 a0, a1_;
    a0.q = *(const uint4*)(wlbf + ((otile * 16 + l15) << 6) + (quad << 3));
    a1_.q = *(const uint4*)(wlbf + ((otile * 16 + l15) << 6) + 32 + (quad << 3));
    floatx4 dz = {0.0f, 0.0f, 0.0f, 0.0f};

    #pragma unroll
    for (int m = 0; m < 2; m++) {
        int nzc = (nzt0 + m) * 16 + l15;
        U8 b0, b1_;
        b0.q = *(const uint4*)(fsT + nzc * 72 + (quad << 3));
        b1_.q = *(const uint4*)(fsT + nzc * 72 + 32 + (quad << 3));
        floatx4 d = __builtin_amdgcn_mfma_f32_16x16x32_bf16(a0.v, b0.v, dz, 0, 0, 0);
        d = __builtin_amdgcn_mfma_f32_16x16x32_bf16(a1_.v, b1_.v, d, 0, 0, 0);
        #pragma unroll
        for (int r = 0; r < 4; r++) {
            int o = otile * 16 + quad * 4 + r;
            float v = d[r] + bias[o];
            unsigned short hv = f2bf(v);
            x0[(((size_t)(b * 32 + o)) << 18) + (nxy << 6) + nzc] = hv;
            ysbf[o * 72 + nzc] = hv;
        }
    }
    __syncthreads();
    {   // forward z-DFT via MFMA: wave (otile, khalf); reduce across khalf via pz
        int khalf = w >> 1;
        U8 ay, bt;
        ay.q = *(const uint4*)(ysbf + (otile * 16 + l15) * 72 + khalf * 32 + (quad << 3));
        bt.q = *(const uint4*)(TfT + (l15 << 6) + khalf * 32 + (quad << 3));
        floatx4 d = __builtin_amdgcn_mfma_f32_16x16x32_bf16(ay.v, bt.v, dz, 0, 0, 0);
        *(floatx4*)(pz + w * 1024 + lane * 4) = d;
    }
    __syncthreads();
    if (w < 2) {
        float4 p0 = *(float4*)(pz + w * 1024 + lane * 4);
        float4 p1 = *(float4*)(pz + (w + 2) * 1024 + lane * 4);
        float* a1f = (float*)a1 + ((size_t)(b * 4096 + nxy)) * 512;
        #pragma unroll
        for (int r = 0; r < 4; r++) {
            int o = otile * 16 + quad * 4 + r;
            float pv[4] = {p0.x + p1.x, p0.y + p1.y, p0.z + p1.z, p0.w + p1.w};
            a1f[(o << 4) + l15] = pv[r];
        }
    }
}

// =================== spectral mid-section: 4 phase kernels ===================

__global__ __launch_bounds__(256) void k_p1(const float2* __restrict__ a1,
                                            float2* __restrict__ a2p) {
    int blk = blockIdx.x, t = threadIdx.x;
    int x = blk & 7, r = blk >> 3;
    int pair = x * 16 + (r & 15);
    int half = r >> 4;
    const float2* src = a1 + ((size_t)(pair * 64 + half * 32)) * 256 + t;
    float accr[8], acci[8];
    #pragma unroll
    for (int k = 0; k < 8; k++) { accr[k] = 0.0f; acci[k] = 0.0f; }
    const float bc = 0.99518472667f;
    const float bs = -0.09801714033f;
    float wc = half ? -1.0f : 1.0f;
    float ws = 0.0f;
    #pragma unroll 4
    for (int j = 0; j < 32; j++) {
        float2 v = src[(size_t)j * 256];
        accr[0] += v.x; acci[0] += v.y;
        float tc = wc, ts = ws;
        #pragma unroll
        for (int ky = 1; ky < 8; ky++) {
            accr[ky] += v.x * tc - v.y * ts;
            acci[ky] += v.x * ts + v.y * tc;
            float nt = tc * wc - ts * ws; ts = ts * wc + tc * ws; tc = nt;
        }
        float nw = wc * bc - ws * bs; ws = ws * bc + wc * bs; wc = nw;
    }
    float4* dst = (float4*)(a2p + (size_t)half * 262144 + ((size_t)(pair * 256 + t)) * 8);
    #pragma unroll
    for (int j = 0; j < 4; j++)
        dst[j] = make_float4(accr[2 * j], acci[2 * j], accr[2 * j + 1], acci[2 * j + 1]);
}

__global__ __launch_bounds__(256) void k_p2(const float2* __restrict__ a2p,
                                            float2* __restrict__ xft) {
    __shared__ __align__(16) float2 SH[1040];
    int blk = blockIdx.x, t = threadIdx.x;
    for (int lu = 0; lu < 2; lu++) {
        int un = blk * 2 + lu;
        int b = un >> 8, ckz = un & 255;
        size_t base = (size_t)b * 131072 + (size_t)ckz * 8;
        for (int e = t; e < 512; e += 256) {
            size_t a = base + (size_t)(e >> 3) * 2048 + (e & 7);
            float2 v0 = a2p[a];
            float2 v1 = a2p[a + 262144];
            SH[lu * 520 + e] = make_float2(v0.x + v1.x, v0.y + v1.y);
        }
    }
    __syncthreads();
    if (t < 128) {
        int lu = t >> 6, out = t & 63;
        int un = blk * 2 + lu;
        int kx = out & 7;
        float sn, cc; sincosf((float)kx * (PI_F / 32.0f), &sn, &cc);
        float bsn = -sn;
        float tc = 1.0f, ts = 0.0f, rr = 0.0f, ri = 0.0f;
        const float2* row = SH + lu * 520 + (out >> 3);
        for (int nx = 0; nx < 64; nx++) {
            float2 v = row[nx * 8];
            rr += v.x * tc - v.y * ts;
            ri += v.x * ts + v.y * tc;
            float nt = tc * cc - ts * bsn; ts = ts * cc + tc * bsn; tc = nt;
        }
        xft[(size_t)un * 64 + out] = make_float2(rr, ri);
    }
}

__global__ __launch_bounds__(256) void k_p3(const float2* __restrict__ xft,
        const float* __restrict__ wr, const float* __restrict__ wi,
        float2* __restrict__ yftp) {
    __shared__ __align__(16) float2 SH[128];
    int blk = blockIdx.x, t = threadIdx.x;
    int unit = blk >> 1, ih = blk & 1;
    int b = unit >> 6, kx = (unit >> 3) & 7, ky = unit & 7;
    if (t < 128) {
        int il = t >> 3, kz = t & 7;
        int i = ih * 16 + il;
        SH[t] = xft[((size_t)((b * 32 + i) * 8 + kz)) * 64 + ky * 8 + kx];
    }
    __syncthreads();
    int o = t >> 3, kz = t & 7;
    float yr = 0.0f, yi = 0.0f;
    for (int il = 0; il < 16; il++) {
        int i = ih * 16 + il;
        float2 xv = SH[il * 8 + kz];
        int wofs = ((i * 32 + o) << 9) + kx * 64 + ky * 8 + kz;
        float wrv = wr[wofs], wiv = wi[wofs];
        yr += xv.x * wrv - xv.y * wiv;
        yi += xv.x * wiv + xv.y * wrv;
    }
    yftp[(size_t)ih * 32768 + ((size_t)((b * 32 + o) * 8 + kz)) * 64 + ky * 8 + kx]
        = make_float2(yr, yi);
}

__global__ __launch_bounds__(256) void k_p4(const float2* __restrict__ yftp,
                                            float2* __restrict__ b1) {
    __shared__ __align__(16) float2 SH[4608];
    int blk = blockIdx.x, t = threadIdx.x;
    for (int u = 0; u < 2; u++) {
        if (u) __syncthreads();
        int unit = blk * 2 + u;
        int b = unit >> 8, nx = (unit >> 2) & 63, og = unit & 3;
        size_t sbase = ((size_t)(b * 32 + og * 8)) * 512;
        for (int e = t; e < 4096; e += 256) {
            float2 v0 = yftp[sbase + e];
            float2 v1 = yftp[32768 + sbase + e];
            SH[(e >> 3) * 9 + (e & 7)] = make_float2(v0.x + v1.x, v0.y + v1.y);
        }
        __syncthreads();
        float cs, ss; sincosf((float)nx * (PI_F / 32.0f), &ss, &cs);
        float2* dst = b1 + ((size_t)(b * 64 + nx)) * 2048 + og * 512;
        for (int h = 0; h < 2; h++) {
            int idx = h * 256 + t;
            const float2* row = SH + idx * 9;
            float c = 1.0f, s = 0.0f, rr = 0.0f, ri = 0.0f;
            #pragma unroll
            for (int kx = 0; kx < 8; kx++) {
                float2 y = row[kx];
                rr += y.x * c - y.y * s;
                ri += y.x * s + y.y * c;
                float nc = c * cs - s * ss; s = s * cs + c * ss; c = nc;
            }
            dst[idx] = make_float2(rr, ri);
        }
    }
}

// ------- k_fin: inverse-y + chained MFMA (bypass + inverse-z) + gelu
//         + (l<3) MFMA forward z-DFT  OR  (l==3) fused projection+residual -------
__global__ __launch_bounds__(256) void k_fin(
        const unsigned short* __restrict__ xin, const float2* __restrict__ b1,
        const unsigned short* __restrict__ wbh, const float* __restrict__ bb,
        const unsigned short* __restrict__ Tinv, const unsigned short* __restrict__ TfT,
        unsigned short* __restrict__ xout, float2* __restrict__ a1, int do_z,
        int do_proj, const float* __restrict__ state_in, const float* __restrict__ p1w,
        const float* __restrict__ p1b, const float* __restrict__ p2w,
        const float* __restrict__ p2b, float* __restrict__ outp) {
    __shared__ __align__(16) float S[7232];
    float* b1sr = S;                              // 2112 (dead after inv-y)
    float* b1si = S + 2112;                       // 2112
    float* pz   = S;                              // 4096 alias (fwd-z partials)
    float* pr   = S;                              // 1024 alias (proj partials)
    unsigned short* xsu  = (unsigned short*)(S + 4224);  // [ch][66] u16 (1056 f)
    unsigned short* msbf = (unsigned short*)(S + 5280);  // [o][40] u16 (640 f)
    unsigned short* ysbf = (unsigned short*)(S + 5920);  // [o][72] u16 (1152 f)
    float* cosT = S + 7072;                       // 64
    float* sinT = S + 7136;                       // 64
    float* bias = S + 7200;                       // 32
    int t = threadIdx.x;
    int b, nx, ny; swz8k(blockIdx.x, b, nx, ny);
    int nxy = nx * 64 + ny;

    if (t < 64) { float s, c; sincosf((float)t * (PI_F / 32.0f), &s, &c); cosT[t] = c; sinT[t] = s; }
    if (t >= 96 && t < 128) bias[t - 96] = bb[t - 96];
    ((unsigned int*)msbf)[(t >> 3) * 20 + 8 + (t & 7)] = 0;   // zero K-pad cols 16..31
    {   // stage x (bf16): one uint4 (8 elems) per thread -> xsu pitch 66
        int ch = t >> 3, q = t & 7;
        uint4 v = *(const uint4*)(xin + (((size_t)b) << 23) + (nxy << 6)
                                  + ((size_t)ch << 18) + q * 8);
        unsigned int* dst = (unsigned int*)(xsu + ch * 66 + q * 8);
        dst[0] = v.x; dst[1] = v.y; dst[2] = v.z; dst[3] = v.w;
    }
    const float2* bsrc = b1 + ((size_t)(b * 64 + nx)) * 2048;   // contiguous 16 KB
    for (int u = 0; u < 8; u++) {
        int g = u * 256 + t;
        float2 v = bsrc[g];
        int ky = g & 7, okz = g >> 3;
        b1sr[ky * 264 + okz] = v.x;
        b1si[ky * 264 + okz] = v.y;
    }
    __syncthreads();
    const float scale = 1.0f / 262144.0f;
    {   // inverse-y (thread t = o*8+kz); write packed bf16 (mr*sc, -mi*sc) to msbf
        float mr = 0.0f, mi = 0.0f;
        #pragma unroll
        for (int ky = 0; ky < 8; ky++) {
            float vr = b1sr[ky * 264 + t], vi = b1si[ky * 264 + t];
            int m_ = (ky * ny) & 63;
            float c = cosT[m_], s = sinT[m_];
            mr += vr * c - vi * s;        // e^{+i ky ny θ}
            mi += vr * s + vi * c;
        }
        int kz = t & 7;
        float sc = (kz == 0) ? scale : 2.0f * scale;
        unsigned int pk = (unsigned int)f2bf(mr * sc)
                        | ((unsigned int)f2bf(-mi * sc) << 16);
        ((unsigned int*)msbf)[(t >> 3) * 20 + kz] = pk;
    }
    __syncthreads();

    // ---- chained MFMA: D = W·X (bypass) + M2·Tinv (inverse-z) ----
    int lane = t & 63;
    int w = rfl(t >> 6);
    int otile = w & 1;
    int nzt0 = (w >> 1) * 2;
    int l15 = lane & 15;
    int quad = lane >> 4;

    U8 aw, ams;
    aw.q = *(const uint4*)(wbh + ((otile * 16 + l15) << 5) + (quad << 3));
    ams.q = *(const uint4*)(msbf + (otile * 16 + l15) * 40 + (quad << 3));

    size_t colbase = (((size_t)b) << 23) + (nxy << 6);
    floatx4 dzero = {0.0f, 0.0f, 0.0f, 0.0f};

    #pragma unroll
    for (int m = 0; m < 2; m++) {
        int nzc = (nzt0 + m) * 16 + l15;
        U8 bx, bt;
        #pragma unroll
        for (int j = 0; j < 8; j++) bx.u[j] = xsu[(quad * 8 + j) * 66 + nzc];
        bt.q = *(const uint4*)(Tinv + (nzc << 5) + (quad << 3));   // global, L1-broadcast
        floatx4 d = __builtin_amdgcn_mfma_f32_16x16x32_bf16(aw.v, bx.v, dzero, 0, 0, 0);
        d = __builtin_amdgcn_mfma_f32_16x16x32_bf16(ams.v, bt.v, d, 0, 0, 0);
        #pragma unroll
        for (int r = 0; r < 4; r++) {
            int o = otile * 16 + quad * 4 + r;
            float gv = gelu_fast(d[r] + bias[o]);
            unsigned short hv = f2bf(gv);
            if (!do_proj) xout[colbase + ((size_t)o << 18) + nzc] = hv;
            ysbf[o * 72 + nzc] = hv;
        }
    }

    if (do_z) {
        __syncthreads();             // b1s region dead -> pz may overwrite
        int khalf = w >> 1;
        U8 ay, bt;
        ay.q = *(const uint4*)(ysbf + (otile * 16 + l15) * 72 + khalf * 32 + (quad << 3));
        bt.q = *(const uint4*)(TfT + (l15 << 6) + khalf * 32 + (quad << 3));
        floatx4 d = __builtin_amdgcn_mfma_f32_16x16x32_bf16(ay.v, bt.v, dzero, 0, 0, 0);
        *(floatx4*)(pz + w * 1024 + lane * 4) = d;
        __syncthreads();
        if (w < 2) {
            float4 p0 = *(float4*)(pz + w * 1024 + lane * 4);
            float4 p1 = *(float4*)(pz + (w + 2) * 1024 + lane * 4);
            float* a1f = (float*)a1 + ((size_t)(b * 4096 + nxy)) * 512;
            float pv[4] = {p0.x + p1.x, p0.y + p1.y, p0.z + p1.z, p0.w + p1.w};
            #pragma unroll
            for (int r = 0; r < 4; r++) {
                int o = otile * 16 + quad * 4 + r;
                a1f[(o << 4) + l15] = pv[r];
            }
        }
    }

    if (do_proj) {                  // fused proj1 -> gelu -> proj2 -> residual
        __syncthreads();            // b1s region dead -> pr may overwrite
        int nz = t & 63;
        float xv[32];
        #pragma unroll
        for (int i = 0; i < 32; i++) xv[i] = bf2f(ysbf[i * 72 + nz]);
        float r0 = 0.f, r1 = 0.f, r2 = 0.f, r3 = 0.f;
        #pragma unroll
        for (int k = 0; k < 8; k++) {
            int o = w * 8 + k;
            float a = p1b[o];                                   // s_load
            const float* wr = p1w + o * 32;                     // s_load
            #pragma unroll
            for (int i = 0; i < 32; i++) a += wr[i] * xv[i];
            float h = gelu_fast(a);
            r0 += p2w[0 * 32 + o] * h;
            r1 += p2w[1 * 32 + o] * h;
            r2 += p2w[2 * 32 + o] * h;
            r3 += p2w[3 * 32 + o] * h;
        }
        *(float4*)(pr + w * 256 + nz * 4) = make_float4(r0, r1, r2, r3);
        __syncthreads();
        if (t < 64) {
            float4 a0 = *(float4*)(pr + 0 * 256 + t * 4);
            float4 a1_ = *(float4*)(pr + 1 * 256 + t * 4);
            float4 a2 = *(float4*)(pr + 2 * 256 + t * 4);
            float4 a3 = *(float4*)(pr + 3 * 256 + t * 4);
            size_t base = ((size_t)b * 262144 + (nxy << 6) + t) * 4;
            float4 sv = *(const float4*)(state_in + base);
            *(float4*)(outp + base) = make_float4(
                sv.x + 0.05f * (p2b[0] + a0.x + a1_.x + a2.x + a3.x),
                sv.y + 0.05f * (p2b[1] + a0.y + a1_.y + a2.y + a3.y),
                sv.z + 0.05f * (p2b[2] + a0.z + a1_.z + a2.z + a3.z),
                sv.w + 0.05f * (p2b[3] + a0.w + a1_.w + a2.w + a3.w));
        }
    }
}

extern "C" void kernel_launch(void* const* d_in, const int* in_sizes, int n_in,
                              void* d_out, int out_size, void* d_ws, size_t ws_size,
                              hipStream_t stream) {
    const float* state_in   = (const float*)d_in[0];
    const float* node_pos   = (const float*)d_in[1];
    const float* time_i     = (const float*)d_in[3];
    const float* conditions = (const float*)d_in[4];
    const float* t_embed_w  = (const float*)d_in[5];
    const float* t_embed_b  = (const float*)d_in[6];
    const float* c_embed_w  = (const float*)d_in[7];
    const float* c_embed_b  = (const float*)d_in[8];
    const float* lift_w     = (const float*)d_in[9];
    const float* lift_b     = (const float*)d_in[10];
    const float* spec_wr    = (const float*)d_in[11];
    const float* spec_wi    = (const float*)d_in[12];
    const float* byp_w      = (const float*)d_in[13];
    const float* byp_b      = (const float*)d_in[14];
    const float* proj1_w    = (const float*)d_in[15];
    const float* proj1_b    = (const float*)d_in[16];
    const float* proj2_w    = (const float*)d_in[17];
    const float* proj2_b    = (const float*)d_in[18];
    float* out = (float*)d_out;
    float* ws  = (float*)d_ws;

    unsigned short* xA = (unsigned short*)ws;                    // 16777216 u16
    unsigned short* xB = (unsigned short*)(ws + 8388608);        // 16777216 u16
    float2* a1   = (float2*)(ws + 16777216);    // 2097152 f2 -> ends 20971520
    float2* a2p  = (float2*)(ws + 20971520);    // 524288 f2  -> ends 22020096
    float2* xft  = (float2*)(ws + 22020096);    // 32768 f2   -> ends 22085632
    float2* yftp = (float2*)(ws + 22085632);    // 65536 f2   -> ends 22216704
    float2* b1   = (float2*)(ws + 22216704);    // 262144 f2  -> ends 22740992
    float*  embk = ws + 22740992;               // 64
    unsigned short* wbh  = (unsigned short*)(ws + 22741056);  // 4096 u16 -> 22743104
    unsigned short* wlbf = (unsigned short*)(ws + 22743104);  // 2048 u16 -> 22744128
    unsigned short* Tinv = (unsigned short*)(ws + 22744128);  // 2048 u16 -> 22745152
    unsigned short* TfT  = (unsigned short*)(ws + 22745152);  // 1024 u16 -> 22745664

    k_emb<<<2, 256, 0, stream>>>(time_i, conditions, t_embed_w, t_embed_b,
                                 c_embed_w, c_embed_b, lift_b, embk);
    k_wt<<<36, 256, 0, stream>>>(byp_w, lift_w, wbh, wlbf, Tinv, TfT);
    k_lift<<<8192, 256, 0, stream>>>(state_in, node_pos, wlbf, embk, TfT, xA, a1);

    for (int l = 0; l < 4; l++) {
        unsigned short* xin  = (l & 1) ? xB : xA;
        unsigned short* xout = (l & 1) ? xA : xB;
        const float* wrl = spec_wr + (size_t)l * 524288;
        const float* wil = spec_wi + (size_t)l * 524288;
        k_p1<<<256, 256, 0, stream>>>(a1, a2p);
        k_p2<<<256, 256, 0, stream>>>(a2p, xft);
        k_p3<<<256, 256, 0, stream>>>(xft, wrl, wil, yftp);
        k_p4<<<256, 256, 0, stream>>>(yftp, b1);
        k_fin<<<8192, 256, 0, stream>>>(xin, b1, wbh + l * 1024, byp_b + l * 32,
                                        Tinv, TfT, xout, a1, (l < 3) ? 1 : 0,
                                        (l == 3) ? 1 : 0, state_in,
                                        proj1_w, proj1_b, proj2_w, proj2_b, out);
    }
}

// Round 13
// 360.632 us; speedup vs baseline: 2.6799x; 1.0419x over previous
//
#include <hip/hip_runtime.h>
#include <math.h>

#define PI_F 3.14159265358979323846f

typedef __bf16 bf16x8 __attribute__((ext_vector_type(8)));
typedef float floatx4 __attribute__((ext_vector_type(4)));
union U8 { unsigned short u[8]; uint4 q; bf16x8 v; };

// sigmoid-form GELU: v * sigmoid(1.702 v) -> 5 VALU (err ~0.01 vs exact; thr 0.099)
__device__ __forceinline__ float gelu_sig(float v) {
    float e = __builtin_amdgcn_exp2f(-2.4554670f * v);   // exp(-1.702 v)
    return v * __builtin_amdgcn_rcpf(1.0f + e);
}
__device__ __forceinline__ int rfl(int x) { return __builtin_amdgcn_readfirstlane(x); }

__device__ __forceinline__ unsigned short f2bf(float f) {   // RNE fp32->bf16
    unsigned int u = __float_as_uint(f);
    u += 0x7fffu + ((u >> 16) & 1u);
    return (unsigned short)(u >> 16);
}
__device__ __forceinline__ float bf2f(unsigned short h) {
    return __uint_as_float(((unsigned int)h) << 16);
}

// XCD-locality swizzle for 8192-block grids (blk%8 -> XCD round-robin).
__device__ __forceinline__ void swz8k(int blk, int& b, int& nx, int& ny) {
    int x = blk & 7;
    int j = blk >> 3;
    int pair = x * 16 + (j >> 6);
    ny = j & 63;
    b = pair >> 6;
    nx = pair & 63;
}

// ---------------- emb ----------------
__global__ void k_emb(const float* __restrict__ time_i, const float* __restrict__ conditions,
                      const float* __restrict__ t_embed_w, const float* __restrict__ t_embed_b,
                      const float* __restrict__ c_embed_w, const float* __restrict__ c_embed_b,
                      const float* __restrict__ lift_b, float* __restrict__ embk) {
    __shared__ float red[8][32];
    int t = threadIdx.x;
    int b = blockIdx.x;
    int c = t & 31, lg = t >> 5;
    float acc = 0.0f;
    if (lg == 0) {
        acc = t_embed_b[c] + c_embed_b[c] + lift_b[c];
        float tv = time_i[b];
        float ang = PI_F * tv;
        const float* tw = t_embed_w + c * 11;
        for (int i = 0; i < 5; i++) {
            float s, co; sincosf(ang, &s, &co);
            acc += co * tw[i] + s * tw[5 + i];
            ang *= 2.0f;
        }
        acc += tv * tw[10];
    }
    const float* cw = c_embed_w + c * 352;
    for (int j = 0; j < 4; j++) {
        int l = lg * 4 + j;
        float v = conditions[b * 32 + l];
        float ang = PI_F * v;
        for (int i = 0; i < 5; i++) {
            float s, co; sincosf(ang, &s, &co);
            acc += co * cw[l * 10 + i] + s * cw[l * 10 + 5 + i];
            ang *= 2.0f;
        }
        acc += v * cw[320 + l];
    }
    red[lg][c] = acc;
    __syncthreads();
    if (t < 32) {
        float s = 0.0f;
        for (int g = 0; g < 8; g++) s += red[g][t];
        embk[b * 32 + t] = s;
    }
}

// -------- k_wt: bf16 constants: bypass W, lift W (K-padded), inv-z / fwd-z twiddles -----
__global__ void k_wt(const float* __restrict__ byp_w, const float* __restrict__ lift_w,
                     unsigned short* __restrict__ wbh, unsigned short* __restrict__ wlbf,
                     unsigned short* __restrict__ Tinv, unsigned short* __restrict__ TfT) {
    int idx = blockIdx.x * 256 + threadIdx.x;
    const float th = PI_F / 32.0f;
    if (idx < 4096) {
        wbh[idx] = f2bf(byp_w[idx]);          // [l][o][i] (A-fragment layout)
    } else if (idx < 6144) {
        int j = idx - 4096;                   // o*64 + q
        int o = j >> 6, q = j & 63;
        wlbf[j] = (q < 37) ? f2bf(lift_w[o * 37 + q]) : 0;
    } else if (idx < 8192) {
        int j = idx - 6144;                   // nz*32 + k
        int nz = j >> 5, k = j & 31;
        int kz = k >> 1;
        float val = 0.0f;
        if (kz < 8) {
            float a = (float)((kz * nz) & 63) * th;
            val = (k & 1) ? sinf(a) : cosf(a);
        }
        Tinv[j] = f2bf(val);
    } else if (idx < 9216) {
        int j = idx - 8192;                   // kcol*64 + nz
        int kcol = j >> 6, nz = j & 63;
        int kz = kcol >> 1;
        float a = (float)((kz * nz) & 63) * th;
        float val = (kcol & 1) ? -sinf(a) : cosf(a);
        TfT[j] = f2bf(val);
    }
}

// ------- k_lift: MFMA lift conv + emb + MFMA forward z-DFT. x0 in bf16. -------
__global__ __launch_bounds__(256) void k_lift(const float* __restrict__ state_in,
        const float* __restrict__ node_pos, const unsigned short* __restrict__ wlbf,
        const float* __restrict__ embk, const unsigned short* __restrict__ TfT,
        unsigned short* __restrict__ x0, float2* __restrict__ a1) {
    __shared__ __align__(16) float SL[7584];
    unsigned short* fsT  = (unsigned short*)SL;          // [nz][72] u16 (2304 f)
    unsigned short* ysbf = (unsigned short*)(SL + 2304); // [o][72] u16 (1152 f)
    float* pz   = SL + 3456;                             // 4096 f (sparse) ; pz2 = pz+512
    float* pz2  = SL + 3456 + 512;                       // 512 f (linear o*16+l15)
    float* bias = SL + 7552;                             // 32
    int t = threadIdx.x;
    int b, nx, ny; swz8k(blockIdx.x, b, nx, ny);
    int nxy = nx * 64 + ny;

    if (t < 32) bias[t] = embk[b * 32 + t];
    {   // zero-pad feature cols 37..68
        for (int u = t; u < 2048; u += 256) {
            int row = u >> 5, col = 37 + (u & 31);
            fsT[row * 72 + col] = 0;
        }
    }
    if (t < 192) {
        int nzf = t / 3;
        int l = t - nzf * 3;
        float p = node_pos[((size_t)b * 262144 + (nxy << 6)) * 3 + t];
        float s, c; sincosf(PI_F * p, &s, &c);
        unsigned short* row = fsT + nzf * 72;
        #pragma unroll
        for (int i = 0; i < 5; i++) {
            row[4 + l * 10 + i] = f2bf(c);
            row[4 + l * 10 + 5 + i] = f2bf(s);
            float nc = 2.0f * c * c - 1.0f;
            s = 2.0f * s * c;
            c = nc;
        }
        row[34 + l] = f2bf(p);
    } else {
        int nzf = t - 192;
        const float4 s4 = *(const float4*)(state_in + ((size_t)b * 262144 + (nxy << 6) + nzf) * 4);
        unsigned short* row = fsT + nzf * 72;
        row[0] = f2bf(s4.x); row[1] = f2bf(s4.y);
        row[2] = f2bf(s4.z); row[3] = f2bf(s4.w);
    }
    __syncthreads();

    int lane = t & 63;
    int w = rfl(t >> 6);
    int otile = w & 1;
    int nzt0 = (w >> 1) * 2;
    int l15 = lane & 15;
    int quad = lane >> 4;

    U8 a0, a1_;
    a0.q = *(const uint4*)(wlbf + ((otile * 16 + l15) << 6) + (quad << 3));
    a1_.q = *(const uint4*)(wlbf + ((otile * 16 + l15) << 6) + 32 + (quad << 3));
    floatx4 cb;
    #pragma unroll
    for (int r = 0; r < 4; r++) cb[r] = bias[otile * 16 + quad * 4 + r];
    floatx4 dz = {0.0f, 0.0f, 0.0f, 0.0f};

    #pragma unroll
    for (int m = 0; m < 2; m++) {
        int nzc = (nzt0 + m) * 16 + l15;
        U8 b0, b1_;
        b0.q = *(const uint4*)(fsT + nzc * 72 + (quad << 3));
        b1_.q = *(const uint4*)(fsT + nzc * 72 + 32 + (quad << 3));
        floatx4 d = __builtin_amdgcn_mfma_f32_16x16x32_bf16(a0.v, b0.v, cb, 0, 0, 0);
        d = __builtin_amdgcn_mfma_f32_16x16x32_bf16(a1_.v, b1_.v, d, 0, 0, 0);
        #pragma unroll
        for (int r = 0; r < 4; r++) {
            int o = otile * 16 + quad * 4 + r;
            ysbf[o * 72 + nzc] = f2bf(d[r]);
        }
    }
    __syncthreads();
    {   // coalesced x0 write: one uint4 (8 bf16) per thread
        int ch = t >> 3, q = t & 7;
        uint4 v = *(const uint4*)(ysbf + ch * 72 + q * 8);
        *(uint4*)(x0 + (((size_t)(b * 32 + ch)) << 18) + (nxy << 6) + q * 8) = v;
    }
    {   // forward z-DFT via MFMA: wave (otile, khalf)
        int khalf = w >> 1;
        U8 ay, bt;
        ay.q = *(const uint4*)(ysbf + (otile * 16 + l15) * 72 + khalf * 32 + (quad << 3));
        bt.q = *(const uint4*)(TfT + (l15 << 6) + khalf * 32 + (quad << 3));
        floatx4 d = __builtin_amdgcn_mfma_f32_16x16x32_bf16(ay.v, bt.v, dz, 0, 0, 0);
        *(floatx4*)(pz + w * 1024 + lane * 4) = d;
    }
    __syncthreads();
    if (w < 2) {
        float4 p0 = *(float4*)(pz + w * 1024 + lane * 4);
        float4 p1 = *(float4*)(pz + (w + 2) * 1024 + lane * 4);
        float pv[4] = {p0.x + p1.x, p0.y + p1.y, p0.z + p1.z, p0.w + p1.w};
        #pragma unroll
        for (int r = 0; r < 4; r++)
            pz2[(otile * 16 + quad * 4 + r) * 16 + l15] = pv[r];   // conflict-free
    }
    __syncthreads();
    if (t < 128) {
        float4 v = *(float4*)(pz2 + t * 4);
        float* a1f = (float*)a1 + ((size_t)(b * 4096 + nxy)) * 512;
        *(float4*)(a1f + t * 4) = v;                               // coalesced 2 KB
    }
}

// =================== spectral mid-section: 4 phase kernels ===================

__global__ __launch_bounds__(256) void k_p1(const float2* __restrict__ a1,
                                            float2* __restrict__ a2p) {
    int blk = blockIdx.x, t = threadIdx.x;
    int x = blk & 7, r = blk >> 3;
    int pair = x * 16 + (r & 15);
    int half = r >> 4;
    const float2* src = a1 + ((size_t)(pair * 64 + half * 32)) * 256 + t;
    float accr[8], acci[8];
    #pragma unroll
    for (int k = 0; k < 8; k++) { accr[k] = 0.0f; acci[k] = 0.0f; }
    const float bc = 0.99518472667f;
    const float bs = -0.09801714033f;
    float wc = half ? -1.0f : 1.0f;
    float ws = 0.0f;
    #pragma unroll 4
    for (int j = 0; j < 32; j++) {
        float2 v = src[(size_t)j * 256];
        accr[0] += v.x; acci[0] += v.y;
        float tc = wc, ts = ws;
        #pragma unroll
        for (int ky = 1; ky < 8; ky++) {
            accr[ky] += v.x * tc - v.y * ts;
            acci[ky] += v.x * ts + v.y * tc;
            float nt = tc * wc - ts * ws; ts = ts * wc + tc * ws; tc = nt;
        }
        float nw = wc * bc - ws * bs; ws = ws * bc + wc * bs; wc = nw;
    }
    float4* dst = (float4*)(a2p + (size_t)half * 262144 + ((size_t)(pair * 256 + t)) * 8);
    #pragma unroll
    for (int j = 0; j < 4; j++)
        dst[j] = make_float4(accr[2 * j], acci[2 * j], accr[2 * j + 1], acci[2 * j + 1]);
}

__global__ __launch_bounds__(256) void k_p2(const float2* __restrict__ a2p,
                                            float2* __restrict__ xft) {
    __shared__ __align__(16) float2 SH[1040];
    int blk = blockIdx.x, t = threadIdx.x;
    for (int lu = 0; lu < 2; lu++) {
        int un = blk * 2 + lu;
        int b = un >> 8, ckz = un & 255;
        size_t base = (size_t)b * 131072 + (size_t)ckz * 8;
        for (int e = t; e < 512; e += 256) {
            size_t a = base + (size_t)(e >> 3) * 2048 + (e & 7);
            float2 v0 = a2p[a];
            float2 v1 = a2p[a + 262144];
            SH[lu * 520 + e] = make_float2(v0.x + v1.x, v0.y + v1.y);
        }
    }
    __syncthreads();
    if (t < 128) {
        int lu = t >> 6, out = t & 63;
        int un = blk * 2 + lu;
        int kx = out & 7;
        float sn, cc; sincosf((float)kx * (PI_F / 32.0f), &sn, &cc);
        float bsn = -sn;
        float tc = 1.0f, ts = 0.0f, rr = 0.0f, ri = 0.0f;
        const float2* row = SH + lu * 520 + (out >> 3);
        for (int nx = 0; nx < 64; nx++) {
            float2 v = row[nx * 8];
            rr += v.x * tc - v.y * ts;
            ri += v.x * ts + v.y * tc;
            float nt = tc * cc - ts * bsn; ts = ts * cc + tc * bsn; tc = nt;
        }
        xft[(size_t)un * 64 + out] = make_float2(rr, ri);
    }
}

__global__ __launch_bounds__(256) void k_p3(const float2* __restrict__ xft,
        const float* __restrict__ wr, const float* __restrict__ wi,
        float2* __restrict__ yftp) {
    __shared__ __align__(16) float2 SH[128];
    int blk = blockIdx.x, t = threadIdx.x;
    int unit = blk >> 1, ih = blk & 1;
    int b = unit >> 6, kx = (unit >> 3) & 7, ky = unit & 7;
    if (t < 128) {
        int il = t >> 3, kz = t & 7;
        int i = ih * 16 + il;
        SH[t] = xft[((size_t)((b * 32 + i) * 8 + kz)) * 64 + ky * 8 + kx];
    }
    __syncthreads();
    int o = t >> 3, kz = t & 7;
    float yr = 0.0f, yi = 0.0f;
    for (int il = 0; il < 16; il++) {
        int i = ih * 16 + il;
        float2 xv = SH[il * 8 + kz];
        int wofs = ((i * 32 + o) << 9) + kx * 64 + ky * 8 + kz;
        float wrv = wr[wofs], wiv = wi[wofs];
        yr += xv.x * wrv - xv.y * wiv;
        yi += xv.x * wiv + xv.y * wrv;
    }
    yftp[(size_t)ih * 32768 + ((size_t)((b * 32 + o) * 8 + kz)) * 64 + ky * 8 + kx]
        = make_float2(yr, yi);
}

__global__ __launch_bounds__(256) void k_p4(const float2* __restrict__ yftp,
                                            float2* __restrict__ b1) {
    __shared__ __align__(16) float2 SH[4608];
    int blk = blockIdx.x, t = threadIdx.x;
    for (int u = 0; u < 2; u++) {
        if (u) __syncthreads();
        int unit = blk * 2 + u;
        int b = unit >> 8, nx = (unit >> 2) & 63, og = unit & 3;
        size_t sbase = ((size_t)(b * 32 + og * 8)) * 512;
        for (int e = t; e < 4096; e += 256) {
            float2 v0 = yftp[sbase + e];
            float2 v1 = yftp[32768 + sbase + e];
            SH[(e >> 3) * 9 + (e & 7)] = make_float2(v0.x + v1.x, v0.y + v1.y);
        }
        __syncthreads();
        float cs, ss; sincosf((float)nx * (PI_F / 32.0f), &ss, &cs);
        float2* dst = b1 + ((size_t)(b * 64 + nx)) * 2048 + og * 512;
        for (int h = 0; h < 2; h++) {
            int idx = h * 256 + t;
            const float2* row = SH + idx * 9;
            float c = 1.0f, s = 0.0f, rr = 0.0f, ri = 0.0f;
            #pragma unroll
            for (int kx = 0; kx < 8; kx++) {
                float2 y = row[kx];
                rr += y.x * c - y.y * s;
                ri += y.x * s + y.y * c;
                float nc = c * cs - s * ss; s = s * cs + c * ss; c = nc;
            }
            dst[idx] = make_float2(rr, ri);
        }
    }
}

// ------- k_fin: inverse-y + chained MFMA (bypass + inverse-z) + gelu
//         + (l<3) MFMA forward z-DFT  OR  (l==3) fused projection+residual -------
__global__ __launch_bounds__(256) void k_fin(
        const unsigned short* __restrict__ xin, const float2* __restrict__ b1,
        const unsigned short* __restrict__ wbh, const float* __restrict__ bb,
        const unsigned short* __restrict__ Tinv, const unsigned short* __restrict__ TfT,
        unsigned short* __restrict__ xout, float2* __restrict__ a1, int do_z,
        int do_proj, const float* __restrict__ state_in, const float* __restrict__ p1w,
        const float* __restrict__ p1b, const float* __restrict__ p2w,
        const float* __restrict__ p2b, float* __restrict__ outp) {
    __shared__ __align__(16) float S[7232];
    float* b1sr = S;                              // 2112 (dead after inv-y)
    float* b1si = S + 2112;                       // 2112
    float* pz   = S;                              // 4096 alias (sparse) ; pz2 = S+512
    float* pz2  = S + 512;                        // 512 alias (linear)
    float* pr   = S;                              // 1024 alias (proj partials)
    unsigned short* xsu  = (unsigned short*)(S + 4224);  // [ch][66] u16 (1056 f)
    unsigned short* msbf = (unsigned short*)(S + 5280);  // [o][40] u16 (640 f)
    unsigned short* ysbf = (unsigned short*)(S + 5920);  // [o][72] u16 (1152 f)
    float* cosT = S + 7072;                       // 64
    float* sinT = S + 7136;                       // 64
    float* bias = S + 7200;                       // 32
    int t = threadIdx.x;
    int b, nx, ny; swz8k(blockIdx.x, b, nx, ny);
    int nxy = nx * 64 + ny;

    if (t < 64) { float s, c; sincosf((float)t * (PI_F / 32.0f), &s, &c); cosT[t] = c; sinT[t] = s; }
    if (t >= 96 && t < 128) bias[t - 96] = bb[t - 96];
    ((unsigned int*)msbf)[(t >> 3) * 20 + 8 + (t & 7)] = 0;   // zero K-pad cols 16..31
    {   // stage x (bf16): one uint4 (8 elems) per thread -> xsu pitch 66
        int ch = t >> 3, q = t & 7;
        uint4 v = *(const uint4*)(xin + (((size_t)b) << 23) + (nxy << 6)
                                  + ((size_t)ch << 18) + q * 8);
        unsigned int* dst = (unsigned int*)(xsu + ch * 66 + q * 8);
        dst[0] = v.x; dst[1] = v.y; dst[2] = v.z; dst[3] = v.w;
    }
    const float2* bsrc = b1 + ((size_t)(b * 64 + nx)) * 2048;   // contiguous 16 KB
    for (int u = 0; u < 8; u++) {
        int g = u * 256 + t;
        float2 v = bsrc[g];
        int ky = g & 7, okz = g >> 3;
        b1sr[ky * 264 + okz] = v.x;
        b1si[ky * 264 + okz] = v.y;
    }
    __syncthreads();
    const float scale = 1.0f / 262144.0f;
    {   // inverse-y (thread t = o*8+kz); write packed bf16 (mr*sc, -mi*sc) to msbf
        float mr = 0.0f, mi = 0.0f;
        #pragma unroll
        for (int ky = 0; ky < 8; ky++) {
            float vr = b1sr[ky * 264 + t], vi = b1si[ky * 264 + t];
            int m_ = (ky * ny) & 63;
            float c = cosT[m_], s = sinT[m_];
            mr += vr * c - vi * s;        // e^{+i ky ny θ}
            mi += vr * s + vi * c;
        }
        int kz = t & 7;
        float sc = (kz == 0) ? scale : 2.0f * scale;
        unsigned int pk = (unsigned int)f2bf(mr * sc)
                        | ((unsigned int)f2bf(-mi * sc) << 16);
        ((unsigned int*)msbf)[(t >> 3) * 20 + kz] = pk;
    }
    __syncthreads();

    // ---- chained MFMA: D = bias + W·X (bypass) + M2·Tinv (inverse-z) ----
    int lane = t & 63;
    int w = rfl(t >> 6);
    int otile = w & 1;
    int nzt0 = (w >> 1) * 2;
    int l15 = lane & 15;
    int quad = lane >> 4;

    U8 aw, ams;
    aw.q = *(const uint4*)(wbh + ((otile * 16 + l15) << 5) + (quad << 3));
    ams.q = *(const uint4*)(msbf + (otile * 16 + l15) * 40 + (quad << 3));
    floatx4 cb;
    #pragma unroll
    for (int r = 0; r < 4; r++) cb[r] = bias[otile * 16 + quad * 4 + r];
    floatx4 dzero = {0.0f, 0.0f, 0.0f, 0.0f};

    size_t colbase = (((size_t)b) << 23) + (nxy << 6);

    #pragma unroll
    for (int m = 0; m < 2; m++) {
        int nzc = (nzt0 + m) * 16 + l15;
        U8 bx, bt;
        #pragma unroll
        for (int j = 0; j < 8; j++) bx.u[j] = xsu[(quad * 8 + j) * 66 + nzc];
        bt.q = *(const uint4*)(Tinv + (nzc << 5) + (quad << 3));   // global, L1-broadcast
        floatx4 d = __builtin_amdgcn_mfma_f32_16x16x32_bf16(aw.v, bx.v, cb, 0, 0, 0);
        d = __builtin_amdgcn_mfma_f32_16x16x32_bf16(ams.v, bt.v, d, 0, 0, 0);
        #pragma unroll
        for (int r = 0; r < 4; r++) {
            int o = otile * 16 + quad * 4 + r;
            ysbf[o * 72 + nzc] = f2bf(gelu_sig(d[r]));
        }
    }
    __syncthreads();

    if (!do_proj) {   // coalesced xout write: one uint4 (8 bf16) per thread
        int ch = t >> 3, q = t & 7;
        uint4 v = *(const uint4*)(ysbf + ch * 72 + q * 8);
        *(uint4*)(xout + colbase + ((size_t)ch << 18) + q * 8) = v;
    }

    if (do_z) {
        int khalf = w >> 1;
        U8 ay, bt;
        ay.q = *(const uint4*)(ysbf + (otile * 16 + l15) * 72 + khalf * 32 + (quad << 3));
        bt.q = *(const uint4*)(TfT + (l15 << 6) + khalf * 32 + (quad << 3));
        floatx4 d = __builtin_amdgcn_mfma_f32_16x16x32_bf16(ay.v, bt.v, dzero, 0, 0, 0);
        *(floatx4*)(pz + w * 1024 + lane * 4) = d;
        __syncthreads();
        if (w < 2) {
            float4 p0 = *(float4*)(pz + w * 1024 + lane * 4);
            float4 p1 = *(float4*)(pz + (w + 2) * 1024 + lane * 4);
            float pv[4] = {p0.x + p1.x, p0.y + p1.y, p0.z + p1.z, p0.w + p1.w};
            #pragma unroll
            for (int r = 0; r < 4; r++)
                pz2[(otile * 16 + quad * 4 + r) * 16 + l15] = pv[r];  // conflict-free
        }
        __syncthreads();
        if (t < 128) {
            float4 v = *(float4*)(pz2 + t * 4);
            float* a1f = (float*)a1 + ((size_t)(b * 4096 + nxy)) * 512;
            *(float4*)(a1f + t * 4) = v;                              // coalesced 2 KB
        }
    }

    if (do_proj) {                  // fused proj1 -> gelu -> proj2 -> residual
        int nz = t & 63;
        float xv[32];
        #pragma unroll
        for (int i = 0; i < 32; i++) xv[i] = bf2f(ysbf[i * 72 + nz]);
        float r0 = 0.f, r1 = 0.f, r2 = 0.f, r3 = 0.f;
        #pragma unroll
        for (int k = 0; k < 8; k++) {
            int o = w * 8 + k;
            float a = p1b[o];                                   // s_load
            const float* wr = p1w + o * 32;                     // s_load
            #pragma unroll
            for (int i = 0; i < 32; i++) a += wr[i] * xv[i];
            float h = gelu_sig(a);
            r0 += p2w[0 * 32 + o] * h;
            r1 += p2w[1 * 32 + o] * h;
            r2 += p2w[2 * 32 + o] * h;
            r3 += p2w[3 * 32 + o] * h;
        }
        *(float4*)(pr + w * 256 + nz * 4) = make_float4(r0, r1, r2, r3);
        __syncthreads();
        if (t < 64) {
            float4 a0 = *(float4*)(pr + 0 * 256 + t * 4);
            float4 a1_ = *(float4*)(pr + 1 * 256 + t * 4);
            float4 a2 = *(float4*)(pr + 2 * 256 + t * 4);
            float4 a3 = *(float4*)(pr + 3 * 256 + t * 4);
            size_t base = ((size_t)b * 262144 + (nxy << 6) + t) * 4;
            float4 sv = *(const float4*)(state_in + base);
            *(float4*)(outp + base) = make_float4(
                sv.x + 0.05f * (p2b[0] + a0.x + a1_.x + a2.x + a3.x),
                sv.y + 0.05f * (p2b[1] + a0.y + a1_.y + a2.y + a3.y),
                sv.z + 0.05f * (p2b[2] + a0.z + a1_.z + a2.z + a3.z),
                sv.w + 0.05f * (p2b[3] + a0.w + a1_.w + a2.w + a3.w));
        }
    }
}

extern "C" void kernel_launch(void* const* d_in, const int* in_sizes, int n_in,
                              void* d_out, int out_size, void* d_ws, size_t ws_size,
                              hipStream_t stream) {
    const float* state_in   = (const float*)d_in[0];
    const float* node_pos   = (const float*)d_in[1];
    const float* time_i     = (const float*)d_in[3];
    const float* conditions = (const float*)d_in[4];
    const float* t_embed_w  = (const float*)d_in[5];
    const float* t_embed_b  = (const float*)d_in[6];
    const float* c_embed_w  = (const float*)d_in[7];
    const float* c_embed_b  = (const float*)d_in[8];
    const float* lift_w     = (const float*)d_in[9];
    const float* lift_b     = (const float*)d_in[10];
    const float* spec_wr    = (const float*)d_in[11];
    const float* spec_wi    = (const float*)d_in[12];
    const float* byp_w      = (const float*)d_in[13];
    const float* byp_b      = (const float*)d_in[14];
    const float* proj1_w    = (const float*)d_in[15];
    const float* proj1_b    = (const float*)d_in[16];
    const float* proj2_w    = (const float*)d_in[17];
    const float* proj2_b    = (const float*)d_in[18];
    float* out = (float*)d_out;
    float* ws  = (float*)d_ws;

    unsigned short* xA = (unsigned short*)ws;                    // 16777216 u16
    unsigned short* xB = (unsigned short*)(ws + 8388608);        // 16777216 u16
    float2* a1   = (float2*)(ws + 16777216);    // 2097152 f2 -> ends 20971520
    float2* a2p  = (float2*)(ws + 20971520);    // 524288 f2  -> ends 22020096
    float2* xft  = (float2*)(ws + 22020096);    // 32768 f2   -> ends 22085632
    float2* yftp = (float2*)(ws + 22085632);    // 65536 f2   -> ends 22216704
    float2* b1   = (float2*)(ws + 22216704);    // 262144 f2  -> ends 22740992
    float*  embk = ws + 22740992;               // 64
    unsigned short* wbh  = (unsigned short*)(ws + 22741056);  // 4096 u16 -> 22743104
    unsigned short* wlbf = (unsigned short*)(ws + 22743104);  // 2048 u16 -> 22744128
    unsigned short* Tinv = (unsigned short*)(ws + 22744128);  // 2048 u16 -> 22745152
    unsigned short* TfT  = (unsigned short*)(ws + 22745152);  // 1024 u16 -> 22745664

    k_emb<<<2, 256, 0, stream>>>(time_i, conditions, t_embed_w, t_embed_b,
                                 c_embed_w, c_embed_b, lift_b, embk);
    k_wt<<<36, 256, 0, stream>>>(byp_w, lift_w, wbh, wlbf, Tinv, TfT);
    k_lift<<<8192, 256, 0, stream>>>(state_in, node_pos, wlbf, embk, TfT, xA, a1);

    for (int l = 0; l < 4; l++) {
        unsigned short* xin  = (l & 1) ? xB : xA;
        unsigned short* xout = (l & 1) ? xA : xB;
        const float* wrl = spec_wr + (size_t)l * 524288;
        const float* wil = spec_wi + (size_t)l * 524288;
        k_p1<<<256, 256, 0, stream>>>(a1, a2p);
        k_p2<<<256, 256, 0, stream>>>(a2p, xft);
        k_p3<<<256, 256, 0, stream>>>(xft, wrl, wil, yftp);
        k_p4<<<256, 256, 0, stream>>>(yftp, b1);
        k_fin<<<8192, 256, 0, stream>>>(xin, b1, wbh + l * 1024, byp_b + l * 32,
                                        Tinv, TfT, xout, a1, (l < 3) ? 1 : 0,
                                        (l == 3) ? 1 : 0, state_in,
                                        proj1_w, proj1_b, proj2_w, proj2_b, out);
    }
}